// Round 2
// baseline (2128.112 us; speedup 1.0000x reference)
//
#include <hip/hip_runtime.h>
#include <hip/hip_bf16.h>

typedef __attribute__((ext_vector_type(8))) short short8;
typedef __attribute__((ext_vector_type(4))) float f32x4;

#define GM 32768   // B*H*W
#define DH 32      // head dim

__device__ __forceinline__ ushort f2bf(float f) {
  unsigned int u = __float_as_uint(f);
  u += 0x7FFFu + ((u >> 16) & 1u);   // round-to-nearest-even
  return (ushort)(u >> 16);
}

// ---- cast fp32 -> bf16, 4 elems/thread ----
__global__ __launch_bounds__(256) void cast_bf16(const float* __restrict__ in,
                                                 ushort* __restrict__ out, int n) {
  int idx = (blockIdx.x * 256 + threadIdx.x) * 4;
  if (idx + 3 < n) {
    float4 t = *(const float4*)(in + idx);
    ushort4 o;
    o.x = f2bf(t.x); o.y = f2bf(t.y); o.z = f2bf(t.z); o.w = f2bf(t.w);
    *(ushort4*)(out + idx) = o;
  }
}

// ---- bf16 MFMA GEMM: C[M,N] = A[M,K] * Bt[N,K]^T (+bias) ----
// MODE 0: qkv epilogue — scale cols<256 by `scale`, scatter to [sel][head][M][32] fp32
// MODE 1: proj epilogue — plain row-major fp32 out + bias
template<int MODE>
__global__ __launch_bounds__(256) void gemm_bt(
    const ushort* __restrict__ A, const ushort* __restrict__ Bt,
    float* __restrict__ C, const float* __restrict__ bias,
    int M, int N, int K, float scale) {
  const int BM = 128, BN = 128, BK = 64;
  __shared__ int4 sA4[BM * BK / 8];   // 16 KB, 16B-chunk XOR swizzled
  __shared__ int4 sB4[BN * BK / 8];   // 16 KB

  int tid = threadIdx.x;
  int lane = tid & 63, wid = tid >> 6;
  int wm = (wid >> 1) * 64, wn = (wid & 1) * 64;   // wave 2x2 -> 64x64 subtile
  int bm = blockIdx.y, bn = blockIdx.x;
  int lo = lane & 15, hi = lane >> 4;

  f32x4 acc[4][4] = {};

  for (int kt = 0; kt < K; kt += BK) {
    int4 ra[4], rb[4];
#pragma unroll
    for (int i = 0; i < 4; ++i) {
      int cid = tid + i * 256;          // 1024 16B chunks per tile
      int r = cid >> 3, c = cid & 7;
      ra[i] = *(const int4*)(A  + (size_t)(bm * BM + r) * K + kt + c * 8);
      rb[i] = *(const int4*)(Bt + (size_t)(bn * BN + r) * K + kt + c * 8);
    }
    __syncthreads();                    // previous iter's ds_reads done
#pragma unroll
    for (int i = 0; i < 4; ++i) {
      int cid = tid + i * 256;
      int r = cid >> 3, c = cid & 7;
      sA4[r * 8 + (c ^ (r & 7))] = ra[i];
      sB4[r * 8 + (c ^ (r & 7))] = rb[i];
    }
    __syncthreads();
#pragma unroll
    for (int ks = 0; ks < 2; ++ks) {
      short8 af[4], bfr[4];
#pragma unroll
      for (int mi = 0; mi < 4; ++mi) {
        int r = wm + mi * 16 + lo;
        int c = ks * 4 + hi;
        af[mi] = ((const short8*)sA4)[r * 8 + (c ^ (r & 7))];
      }
#pragma unroll
      for (int nj = 0; nj < 4; ++nj) {
        int r = wn + nj * 16 + lo;
        int c = ks * 4 + hi;
        bfr[nj] = ((const short8*)sB4)[r * 8 + (c ^ (r & 7))];
      }
#pragma unroll
      for (int mi = 0; mi < 4; ++mi)
#pragma unroll
        for (int nj = 0; nj < 4; ++nj)
          acc[mi][nj] = __builtin_amdgcn_mfma_f32_16x16x32_bf16(
              af[mi], bfr[nj], acc[mi][nj], 0, 0, 0);
    }
  }

#pragma unroll
  for (int mi = 0; mi < 4; ++mi) {
#pragma unroll
    for (int nj = 0; nj < 4; ++nj) {
#pragma unroll
      for (int r = 0; r < 4; ++r) {
        int row = bm * BM + wm + mi * 16 + hi * 4 + r;   // C/D: col=lane&15, row=(lane>>4)*4+reg
        int col = bn * BN + wn + nj * 16 + lo;
        float v = acc[mi][nj][r] + bias[col];
        if (MODE == 0) {
          if (col < 256) v *= scale;                     // q pre-scale
          int sel = col >> 8, h = (col >> 5) & 7, d = col & 31;
          C[((size_t)(sel * 8 + h) * M + row) * DH + d] = v;
        } else {
          C[(size_t)row * N + col] = v;
        }
      }
    }
  }
}

// ---- neighborhood attention v2: one WAVE per (b,h,row-i); lane = j ----
// fp32 K/V from qkv buffer; 4-way split dot chains; no-max softmax (logits bounded).
template<int KS>
__device__ __forceinline__ void natt_row(const float* __restrict__ qkv,
                                         const float* __restrict__ rpb,
                                         ushort* __restrict__ y,
                                         int b, int hl, int h, int i) {
  const int L = 64, NHF = KS / 2, BWD = 2 * KS - 1;
  int j = threadIdx.x;                     // 0..63

  int wi = i - NHF; wi = wi < 0 ? 0 : wi; wi = wi > (L - KS) ? (L - KS) : wi;
  int pi = NHF + ((i < NHF) ? (NHF - i) : 0) + ((i >= L - NHF) ? (L - 1 - NHF - i) : 0);
  int wj = j - NHF; wj = wj < 0 ? 0 : wj; wj = wj > (L - KS) ? (L - KS) : wj;
  int pj = NHF + ((j < NHF) ? (NHF - j) : 0) + ((j >= L - NHF) ? (L - 1 - NHF - j) : 0);

  size_t pos = (size_t)(b * 64 + i) * 64 + j;
  const float* qp = qkv + ((size_t)h * GM + pos) * DH;
  const float* kb = qkv + ((size_t)(8 + h) * GM + (size_t)b * 4096 + (size_t)(wi * 64 + wj)) * DH;
  const float* vb = qkv + ((size_t)(16 + h) * GM + (size_t)b * 4096 + (size_t)(wi * 64 + wj)) * DH;
  const float* bias = rpb + ((size_t)hl * BWD + pi) * BWD + pj;

  float4 q[8];
#pragma unroll
  for (int c = 0; c < 8; ++c) q[c] = ((const float4*)qp)[c];

  float4 a[8] = {};
  float lsum = 0.f;

  for (int ki = 0; ki < KS; ++ki) {
    const float* kr = kb + (size_t)ki * 64 * DH;
    const float* vr = vb + (size_t)ki * 64 * DH;
    const float* br = bias + ki * BWD;
    for (int kj = 0; kj < KS; ++kj) {
      const float4* kp = (const float4*)(kr + kj * DH);
      // 4 independent partial chains (8 FMA deep each) instead of one 32-deep chain
      float s0 = q[0].x*kp[0].x + q[0].y*kp[0].y + q[0].z*kp[0].z + q[0].w*kp[0].w
               + q[4].x*kp[4].x + q[4].y*kp[4].y + q[4].z*kp[4].z + q[4].w*kp[4].w;
      float s1 = q[1].x*kp[1].x + q[1].y*kp[1].y + q[1].z*kp[1].z + q[1].w*kp[1].w
               + q[5].x*kp[5].x + q[5].y*kp[5].y + q[5].z*kp[5].z + q[5].w*kp[5].w;
      float s2 = q[2].x*kp[2].x + q[2].y*kp[2].y + q[2].z*kp[2].z + q[2].w*kp[2].w
               + q[6].x*kp[6].x + q[6].y*kp[6].y + q[6].z*kp[6].z + q[6].w*kp[6].w;
      float s3 = q[3].x*kp[3].x + q[3].y*kp[3].y + q[3].z*kp[3].z + q[3].w*kp[3].w
               + q[7].x*kp[7].x + q[7].y*kp[7].y + q[7].z*kp[7].z + q[7].w*kp[7].w;
      float p = __expf((s0 + s1) + (s2 + s3) + br[kj]);   // logits bounded -> no max
      lsum += p;
      const float4* vp = (const float4*)(vr + kj * DH);
#pragma unroll
      for (int c = 0; c < 8; ++c) {
        a[c].x += p * vp[c].x; a[c].y += p * vp[c].y;
        a[c].z += p * vp[c].z; a[c].w += p * vp[c].w;
      }
    }
  }

  float inv = 1.f / lsum;
  unsigned int pw[8];
#pragma unroll
  for (int c = 0; c < 8; ++c) {
    pw[c] = (unsigned int)f2bf(a[c].x * inv) | ((unsigned int)f2bf(a[c].y * inv) << 16);
    ++c;
    --c;
  }
  // repack: 2 floats per uint; need 16 uints total -> recompute cleanly
  unsigned int w16[16];
#pragma unroll
  for (int c = 0; c < 8; ++c) {
    w16[2*c]   = (unsigned int)f2bf(a[c].x * inv) | ((unsigned int)f2bf(a[c].y * inv) << 16);
    w16[2*c+1] = (unsigned int)f2bf(a[c].z * inv) | ((unsigned int)f2bf(a[c].w * inv) << 16);
  }
  uint4* yp4 = (uint4*)(y + pos * 256 + h * DH);
#pragma unroll
  for (int c = 0; c < 4; ++c)
    yp4[c] = make_uint4(w16[4*c], w16[4*c+1], w16[4*c+2], w16[4*c+3]);
}

__global__ __launch_bounds__(64, 4) void natt_all(const float* __restrict__ qkv,
    const float* __restrict__ rpb0, const float* __restrict__ rpb1,
    ushort* __restrict__ y) {
  int blk = blockIdx.x;          // 4096 = 8b * 8h * 64i
  int i = blk & 63;
  int rest = blk >> 6;           // b*8 + ho
  int b = rest >> 3;
  int ho = rest & 7;
  // K13 heads (h=4..7) dispatched first within each b for balance
  if (ho < 4) natt_row<13>(qkv, rpb1, y, b, ho, ho + 4, i);
  else        natt_row<7> (qkv, rpb0, y, b, ho - 4, ho - 4, i);
}

extern "C" void kernel_launch(void* const* d_in, const int* in_sizes, int n_in,
                              void* d_out, int out_size, void* d_ws, size_t ws_size,
                              hipStream_t stream) {
  const float* x      = (const float*)d_in[0];
  const float* w_qkv  = (const float*)d_in[1];
  const float* b_qkv  = (const float*)d_in[2];
  const float* rpb0   = (const float*)d_in[3];
  const float* rpb1   = (const float*)d_in[4];
  const float* w_proj = (const float*)d_in[5];
  const float* b_proj = (const float*)d_in[6];
  float* out = (float*)d_out;

  char* ws = (char*)d_ws;
  ushort* xb  = (ushort*)(ws);                                          // 16 MB
  ushort* wqb = (ushort*)(ws + 16777216);                               // 384 KB
  ushort* wpb = (ushort*)(ws + 16777216 + 393216);                      // 128 KB
  float*  qkv = (float*)(ws + 16777216 + 393216 + 131072);              // 96 MB: [3][8][32768][32]
  ushort* yb  = (ushort*)(ws + 16777216 + 393216 + 131072 + 100663296); // 16 MB: [32768][256]

  cast_bf16<<<8192, 256, 0, stream>>>(x, xb, 8388608);
  cast_bf16<<<192, 256, 0, stream>>>(w_qkv, wqb, 196608);
  cast_bf16<<<64, 256, 0, stream>>>(w_proj, wpb, 65536);
  gemm_bt<0><<<dim3(6, 256), 256, 0, stream>>>(xb, wqb, qkv, b_qkv,
                                               32768, 768, 256, 0.17677669529663687f);
  natt_all<<<4096, 64, 0, stream>>>(qkv, rpb0, rpb1, yb);
  gemm_bt<1><<<dim3(2, 256), 256, 0, stream>>>(yb, wpb, out, b_proj,
                                               32768, 256, 256, 1.0f);
}

// Round 3
// 291.234 us; speedup vs baseline: 7.3072x; 7.3072x over previous
//
#include <hip/hip_runtime.h>
#include <hip/hip_bf16.h>

typedef __attribute__((ext_vector_type(8))) short short8;
typedef __attribute__((ext_vector_type(4))) float f32x4;

#define GM 32768   // B*H*W
#define DH 32      // head dim

__device__ __forceinline__ ushort f2bf(float f) {
  unsigned int u = __float_as_uint(f);
  u += 0x7FFFu + ((u >> 16) & 1u);   // round-to-nearest-even
  return (ushort)(u >> 16);
}
__device__ __forceinline__ float bf2f(ushort u) {
  return __uint_as_float(((unsigned int)u) << 16);
}

// ---- cast fp32 -> bf16 ----
__global__ __launch_bounds__(256) void cast_bf16(const float* __restrict__ in,
                                                 ushort* __restrict__ out, int n) {
  int idx = (blockIdx.x * 256 + threadIdx.x) * 4;
  if (idx + 3 < n) {
    float4 t = *(const float4*)(in + idx);
    ushort4 o;
    o.x = f2bf(t.x); o.y = f2bf(t.y); o.z = f2bf(t.z); o.w = f2bf(t.w);
    *(ushort4*)(out + idx) = o;
  }
}

// ---- bf16 MFMA GEMM: C = A * Bt^T + bias ----
// MODE 0: qkv epilogue -> bf16 scatter to [sel*8+h][pos][32] (q scaled)
// MODE 1: proj epilogue -> fp32 row-major
template<int MODE>
__global__ __launch_bounds__(256) void gemm_bt(
    const ushort* __restrict__ A, const ushort* __restrict__ Bt,
    ushort* __restrict__ Cb, float* __restrict__ Cf, const float* __restrict__ bias,
    int M, int N, int K, float scale) {
  const int BM = 128, BN = 128, BK = 64;
  __shared__ int4 sA4[BM * BK / 8];
  __shared__ int4 sB4[BN * BK / 8];

  int tid = threadIdx.x;
  int lane = tid & 63, wid = tid >> 6;
  int wm = (wid >> 1) * 64, wn = (wid & 1) * 64;
  int bm = blockIdx.y, bn = blockIdx.x;
  int lo = lane & 15, hi = lane >> 4;

  f32x4 acc[4][4] = {};

  for (int kt = 0; kt < K; kt += BK) {
    int4 ra[4], rb[4];
#pragma unroll
    for (int i = 0; i < 4; ++i) {
      int cid = tid + i * 256;
      int r = cid >> 3, c = cid & 7;
      ra[i] = *(const int4*)(A  + (size_t)(bm * BM + r) * K + kt + c * 8);
      rb[i] = *(const int4*)(Bt + (size_t)(bn * BN + r) * K + kt + c * 8);
    }
    __syncthreads();
#pragma unroll
    for (int i = 0; i < 4; ++i) {
      int cid = tid + i * 256;
      int r = cid >> 3, c = cid & 7;
      sA4[r * 8 + (c ^ (r & 7))] = ra[i];
      sB4[r * 8 + (c ^ (r & 7))] = rb[i];
    }
    __syncthreads();
#pragma unroll
    for (int ks = 0; ks < 2; ++ks) {
      short8 af[4], bfr[4];
#pragma unroll
      for (int mi = 0; mi < 4; ++mi) {
        int r = wm + mi * 16 + lo, c = ks * 4 + hi;
        af[mi] = ((const short8*)sA4)[r * 8 + (c ^ (r & 7))];
      }
#pragma unroll
      for (int nj = 0; nj < 4; ++nj) {
        int r = wn + nj * 16 + lo, c = ks * 4 + hi;
        bfr[nj] = ((const short8*)sB4)[r * 8 + (c ^ (r & 7))];
      }
#pragma unroll
      for (int mi = 0; mi < 4; ++mi)
#pragma unroll
        for (int nj = 0; nj < 4; ++nj)
          acc[mi][nj] = __builtin_amdgcn_mfma_f32_16x16x32_bf16(
              af[mi], bfr[nj], acc[mi][nj], 0, 0, 0);
    }
  }

#pragma unroll
  for (int mi = 0; mi < 4; ++mi) {
#pragma unroll
    for (int nj = 0; nj < 4; ++nj) {
#pragma unroll
      for (int r = 0; r < 4; ++r) {
        int row = bm * BM + wm + mi * 16 + hi * 4 + r;
        int col = bn * BN + wn + nj * 16 + lo;
        float v = acc[mi][nj][r] + bias[col];
        if (MODE == 0) {
          int sel = col >> 8;
          if (sel == 0) v *= scale;
          int hh = (col >> 5) & 7, d = col & 31;
          Cb[((size_t)(sel * 8 + hh) * GM + row) * DH + d] = f2bf(v);
        } else {
          Cf[(size_t)row * N + col] = v;
        }
      }
    }
  }
}

// ---- transpose V: [h][pos][32] bf16 -> vt [h][32][pos] bf16 ----
__global__ __launch_bounds__(256) void transpose_v(const ushort* __restrict__ vsrc,
                                                   ushort* __restrict__ vt) {
  __shared__ ushort tile[DH][264];   // +8 pad: spreads d-rows across bank groups
  int hb = blockIdx.x >> 7;
  int pb = (blockIdx.x & 127) << 8;
  int t = threadIdx.x;
  const ushort* src = vsrc + ((size_t)hb * GM + pb + t) * DH;
  short8 rbuf[4];
#pragma unroll
  for (int c4 = 0; c4 < 4; ++c4) rbuf[c4] = *(const short8*)(src + c4 * 8);
#pragma unroll
  for (int c4 = 0; c4 < 4; ++c4)
#pragma unroll
    for (int e = 0; e < 8; ++e)
      tile[c4 * 8 + e][t] = (ushort)rbuf[c4][e];
  __syncthreads();
  int d = t >> 3, seg = t & 7;
  ushort* dst = vt + ((size_t)hb * DH + d) * GM + pb + seg * 32;
  const ushort* srow = &tile[d][seg * 32];
#pragma unroll
  for (int c4 = 0; c4 < 4; ++c4)
    *(short8*)(dst + c4 * 8) = *(const short8*)(srow + c4 * 8);
}

// ---- MFMA neighborhood attention: block = (b,h,i-row), 4 waves x 16 queries ----
template<int KS>
__device__ __forceinline__ void natt_row(const ushort* __restrict__ qkvb,
                                         const ushort* __restrict__ vt,
                                         const float* __restrict__ rpb,
                                         ushort* __restrict__ y,
                                         float* sbias, ushort* sP,
                                         int b, int hl, int h, int i) {
  const int NHF = KS / 2, BW = 2 * KS - 1, LK = 64 - KS;
  int tid = threadIdx.x;
  int lane = tid & 63, w = tid >> 6, lo = lane & 15, hi = lane >> 4;

  int wi = i - NHF; wi = wi < 0 ? 0 : (wi > LK ? LK : wi);
  int pi = NHF + ((i < NHF) ? (NHF - i) : 0) + ((i >= 64 - NHF) ? (63 - NHF - i) : 0);

  // stage Toeplitz bias rows: bias(i,j,ki,c) = rpb[hl][pi+ki][(KS-1)+c-j]
  for (int t = tid; t < KS * BW; t += 256) {
    int ki = t / BW, cb = t - ki * BW;
    sbias[t] = rpb[((size_t)hl * BW + pi + ki) * BW + cb];
  }
  __syncthreads();

  const ushort* qb = qkvb;                       // [8][GM][32]
  const ushort* kb = qkvb + (size_t)8 * GM * DH; // [8][GM][32]

  size_t posQ = (size_t)h * GM + b * 4096 + i * 64 + 16 * w + lo;
  short8 aq = *(const short8*)(qb + posQ * DH + hi * 8);   // A-frag: Q[j=lo][k=hi*8+e]

  int jbase = 16 * w;
  int wj16 = jbase - NHF; wj16 = wj16 < 0 ? 0 : (wj16 > LK ? LK : wj16);
  int cbase = wj16 < 32 ? wj16 : 32;   // 32-wide key band covers all 16 queries' windows

  int wj_r[4], j_r[4];
#pragma unroll
  for (int r = 0; r < 4; ++r) {
    int j = jbase + hi * 4 + r;
    j_r[r] = j;
    int t2 = j - NHF; t2 = t2 < 0 ? 0 : (t2 > LK ? LK : t2);
    wj_r[r] = t2;
  }

  ushort* sPw = sP + w * 16 * 32;   // per-wave P tile [16][32], chunk-XOR swizzled

  f32x4 o0 = {}, o1 = {};
  float den[4] = {0.f, 0.f, 0.f, 0.f};
  const f32x4 zero = {};

  for (int ki = 0; ki < KS; ++ki) {
    const ushort* krow = kb + ((size_t)h * GM + b * 4096 + (wi + ki) * 64 + cbase) * DH;
    short8 bk0 = *(const short8*)(krow + lo * DH + hi * 8);
    short8 bk1 = *(const short8*)(krow + (16 + lo) * DH + hi * 8);
    f32x4 s0 = __builtin_amdgcn_mfma_f32_16x16x32_bf16(aq, bk0, zero, 0, 0, 0);
    f32x4 s1 = __builtin_amdgcn_mfma_f32_16x16x32_bf16(aq, bk1, zero, 0, 0, 0);

    const float* brow = sbias + ki * BW;
#pragma unroll
    for (int nt = 0; nt < 2; ++nt) {
      int c = cbase + nt * 16 + lo;
#pragma unroll
      for (int r = 0; r < 4; ++r) {
        float sv = (nt == 0) ? s0[r] : s1[r];
        int kj = c - wj_r[r];
        int idx = c - j_r[r] + (KS - 1);
        idx = idx < 0 ? 0 : (idx > BW - 1 ? BW - 1 : idx);
        float tl = sv + brow[idx];
        float p = (kj >= 0 && kj < KS) ? __expf(tl) : 0.f;   // logits bounded: no max
        ushort pq = f2bf(p);
        den[r] += bf2f(pq);   // denominator from QUANTIZED weights (matches numerator)
        int jr = hi * 4 + r;
        int chunk = (nt * 2 + (lo >> 3)) ^ (jr >> 2);
        *(ushort*)((char*)sPw + jr * 64 + chunk * 16 + ((lo & 7) << 1)) = pq;
      }
    }
    // P A-frag: row j'=lo, k-chunk hi (same-wave LDS, in-order -> no barrier)
    short8 pa = *(const short8*)((char*)sPw + lo * 64 + ((hi ^ (lo >> 2)) << 4));
    // V B-frags from transposed vt: B[k=c][n=d], lane: d=lo(+16), c=hi*8+e
    size_t vrow = (size_t)b * 4096 + (wi + ki) * 64 + cbase + hi * 8;
    short8 v0 = *(const short8*)(vt + ((size_t)h * DH + lo) * GM + vrow);
    short8 v1 = *(const short8*)(vt + ((size_t)h * DH + 16 + lo) * GM + vrow);
    o0 = __builtin_amdgcn_mfma_f32_16x16x32_bf16(pa, v0, o0, 0, 0, 0);
    o1 = __builtin_amdgcn_mfma_f32_16x16x32_bf16(pa, v1, o1, 0, 0, 0);
  }

  // denominator: reduce over the 16-lane lo-group (same hi)
#pragma unroll
  for (int r = 0; r < 4; ++r) {
    float d = den[r];
    d += __shfl_xor(d, 1);
    d += __shfl_xor(d, 2);
    d += __shfl_xor(d, 4);
    d += __shfl_xor(d, 8);
    den[r] = 1.f / d;
  }

  size_t ybase = ((size_t)b * 4096 + (size_t)i * 64) * 256 + h * DH;
#pragma unroll
  for (int r = 0; r < 4; ++r) {
    y[ybase + (size_t)j_r[r] * 256 + lo]      = f2bf(o0[r] * den[r]);
    y[ybase + (size_t)j_r[r] * 256 + 16 + lo] = f2bf(o1[r] * den[r]);
  }
}

__global__ __launch_bounds__(256) void natt_mfma(const ushort* __restrict__ qkvb,
    const ushort* __restrict__ vt, const float* __restrict__ rpb0,
    const float* __restrict__ rpb1, ushort* __restrict__ y) {
  __shared__ float sbias[13 * 25];
  __shared__ ushort sP[4 * 16 * 32];
  int blk = blockIdx.x;
  int i = blk & 63;
  int rest = blk >> 6;
  int b = rest >> 3, ho = rest & 7;
  if (ho < 4) natt_row<13>(qkvb, vt, rpb1, y, sbias, sP, b, ho, ho + 4, i);
  else        natt_row<7> (qkvb, vt, rpb0, y, sbias, sP, b, ho - 4, ho - 4, i);
}

extern "C" void kernel_launch(void* const* d_in, const int* in_sizes, int n_in,
                              void* d_out, int out_size, void* d_ws, size_t ws_size,
                              hipStream_t stream) {
  const float* x      = (const float*)d_in[0];
  const float* w_qkv  = (const float*)d_in[1];
  const float* b_qkv  = (const float*)d_in[2];
  const float* rpb0   = (const float*)d_in[3];
  const float* rpb1   = (const float*)d_in[4];
  const float* w_proj = (const float*)d_in[5];
  const float* b_proj = (const float*)d_in[6];
  float* out = (float*)d_out;

  char* ws = (char*)d_ws;
  ushort* xb   = (ushort*)(ws);                               // 16 MB
  ushort* wqb  = (ushort*)(ws + (16u << 20));                 // 384 KB
  ushort* wpb  = (ushort*)(ws + (16u << 20) + 393216);        // 128 KB
  ushort* qkvb = (ushort*)(ws + (16u << 20) + 524288);        // 48 MB: [24][32768][32] bf16
  ushort* vt   = (ushort*)(ws + (64u << 20) + 524288);        // 16 MB: [8][32][32768] bf16
  ushort* yb   = (ushort*)(ws + (80u << 20) + 524288);        // 16 MB: [32768][256] bf16

  cast_bf16<<<8192, 256, 0, stream>>>(x, xb, 8388608);
  cast_bf16<<<192, 256, 0, stream>>>(w_qkv, wqb, 196608);
  cast_bf16<<<64, 256, 0, stream>>>(w_proj, wpb, 65536);
  gemm_bt<0><<<dim3(6, 256), 256, 0, stream>>>(xb, wqb, qkvb, nullptr, b_qkv,
                                               32768, 768, 256, 0.17677669529663687f);
  transpose_v<<<1024, 256, 0, stream>>>(qkvb + (size_t)16 * GM * DH, vt);
  natt_mfma<<<4096, 256, 0, stream>>>(qkvb, vt, rpb0, rpb1, yb);
  gemm_bt<1><<<dim3(2, 256), 256, 0, stream>>>(yb, wpb, nullptr, out, b_proj,
                                               32768, 256, 256, 1.0f);
}

// Round 4
// 280.281 us; speedup vs baseline: 7.5928x; 1.0391x over previous
//
#include <hip/hip_runtime.h>
#include <hip/hip_bf16.h>

typedef __attribute__((ext_vector_type(8))) short short8;
typedef __attribute__((ext_vector_type(4))) float f32x4;

#define GM 32768   // B*H*W
#define DH 32      // head dim
#define LOG2E 1.4426950408889634f

__device__ __forceinline__ ushort f2bf(float f) {
  unsigned int u = __float_as_uint(f);
  u += 0x7FFFu + ((u >> 16) & 1u);   // round-to-nearest-even
  return (ushort)(u >> 16);
}

// ---- fused cast fp32 -> bf16 for x, w_qkv, w_proj (one launch) ----
__global__ __launch_bounds__(256) void cast_all(
    const float* __restrict__ x, const float* __restrict__ wq, const float* __restrict__ wp,
    ushort* __restrict__ xb, ushort* __restrict__ wqb, ushort* __restrict__ wpb) {
  int bid = blockIdx.x;
  const float* src; ushort* dst; int base;
  if (bid < 8192)      { src = x;  dst = xb;  base = bid * 1024; }
  else if (bid < 8384) { src = wq; dst = wqb; base = (bid - 8192) * 1024; }
  else                 { src = wp; dst = wpb; base = (bid - 8384) * 1024; }
  int idx = base + threadIdx.x * 4;
  float4 t = *(const float4*)(src + idx);
  ushort4 o;
  o.x = f2bf(t.x); o.y = f2bf(t.y); o.z = f2bf(t.z); o.w = f2bf(t.w);
  *(ushort4*)(dst + idx) = o;
}

// ---- bf16 MFMA GEMM: C = A * Bt^T + bias, XCD-swizzled 1D grid ----
// MODE 0: grid 1536 (N=768): qkv epilogue -> bf16 scatter [sel*8+h][pos][32], q scaled
// MODE 1: grid 512  (N=256): proj epilogue -> fp32 row-major
template<int MODE>
__global__ __launch_bounds__(256) void gemm_bt(
    const ushort* __restrict__ A, const ushort* __restrict__ Bt,
    ushort* __restrict__ Cb, float* __restrict__ Cf, const float* __restrict__ bias,
    int M, int N, int K, float scale) {
  const int BM = 128, BN = 128, BK = 64;
  __shared__ int4 sA4[BM * BK / 8];
  __shared__ int4 sB4[BN * BK / 8];

  // XCD-aware decode: same-bm blocks land on one XCD (A-tile L2 reuse)
  int id = blockIdx.x;
  int xcd = id & 7, rest = id >> 3;
  int bm, bn;
  if (MODE == 0) { bm = xcd * 32 + rest / 6;    bn = rest % 6; }
  else           { bm = xcd * 32 + (rest >> 1); bn = rest & 1; }

  int tid = threadIdx.x;
  int lane = tid & 63, wid = tid >> 6;
  int wm = (wid >> 1) * 64, wn = (wid & 1) * 64;
  int lo = lane & 15, hi = lane >> 4;

  f32x4 acc[4][4] = {};

  for (int kt = 0; kt < K; kt += BK) {
    int4 ra[4], rb[4];
#pragma unroll
    for (int i = 0; i < 4; ++i) {
      int cid = tid + i * 256;
      int r = cid >> 3, c = cid & 7;
      ra[i] = *(const int4*)(A  + (size_t)(bm * BM + r) * K + kt + c * 8);
      rb[i] = *(const int4*)(Bt + (size_t)(bn * BN + r) * K + kt + c * 8);
    }
    __syncthreads();
#pragma unroll
    for (int i = 0; i < 4; ++i) {
      int cid = tid + i * 256;
      int r = cid >> 3, c = cid & 7;
      sA4[r * 8 + (c ^ (r & 7))] = ra[i];
      sB4[r * 8 + (c ^ (r & 7))] = rb[i];
    }
    __syncthreads();
#pragma unroll
    for (int ks = 0; ks < 2; ++ks) {
      short8 af[4], bfr[4];
#pragma unroll
      for (int mi = 0; mi < 4; ++mi) {
        int r = wm + mi * 16 + lo, c = ks * 4 + hi;
        af[mi] = ((const short8*)sA4)[r * 8 + (c ^ (r & 7))];
      }
#pragma unroll
      for (int nj = 0; nj < 4; ++nj) {
        int r = wn + nj * 16 + lo, c = ks * 4 + hi;
        bfr[nj] = ((const short8*)sB4)[r * 8 + (c ^ (r & 7))];
      }
#pragma unroll
      for (int mi = 0; mi < 4; ++mi)
#pragma unroll
        for (int nj = 0; nj < 4; ++nj)
          acc[mi][nj] = __builtin_amdgcn_mfma_f32_16x16x32_bf16(
              af[mi], bfr[nj], acc[mi][nj], 0, 0, 0);
    }
  }

#pragma unroll
  for (int mi = 0; mi < 4; ++mi) {
#pragma unroll
    for (int nj = 0; nj < 4; ++nj) {
#pragma unroll
      for (int r = 0; r < 4; ++r) {
        int row = bm * BM + wm + mi * 16 + hi * 4 + r;
        int col = bn * BN + wn + nj * 16 + lo;
        float v = acc[mi][nj][r] + bias[col];
        if (MODE == 0) {
          int sel = col >> 8;
          if (sel == 0) v *= scale;      // q * hd^-0.5 * log2e (exp2 path)
          int hh = (col >> 5) & 7, d = col & 31;
          Cb[((size_t)(sel * 8 + hh) * GM + row) * DH + d] = f2bf(v);
        } else {
          Cf[(size_t)row * N + col] = v;
        }
      }
    }
  }
}

// ---- transpose V: [h][pos][32] bf16 -> vt [h][32][pos] bf16 ----
__global__ __launch_bounds__(256) void transpose_v(const ushort* __restrict__ vsrc,
                                                   ushort* __restrict__ vt) {
  __shared__ ushort tile[DH][264];
  int hb = blockIdx.x >> 7;
  int pb = (blockIdx.x & 127) << 8;
  int t = threadIdx.x;
  const ushort* src = vsrc + ((size_t)hb * GM + pb + t) * DH;
  short8 rbuf[4];
#pragma unroll
  for (int c4 = 0; c4 < 4; ++c4) rbuf[c4] = *(const short8*)(src + c4 * 8);
#pragma unroll
  for (int c4 = 0; c4 < 4; ++c4)
#pragma unroll
    for (int e = 0; e < 8; ++e)
      tile[c4 * 8 + e][t] = (ushort)rbuf[c4][e];
  __syncthreads();
  int d = t >> 3, seg = t & 7;
  ushort* dst = vt + ((size_t)hb * DH + d) * GM + pb + seg * 32;
  const ushort* srow = &tile[d][seg * 32];
#pragma unroll
  for (int c4 = 0; c4 < 4; ++c4)
    *(short8*)(dst + c4 * 8) = *(const short8*)(srow + c4 * 8);
}

// ---- MFMA neighborhood attention v2: swapped QK^T (lane owns one query) ----
template<int KS>
__device__ __forceinline__ void natt_row(const ushort* __restrict__ qkvb,
                                         const ushort* __restrict__ vt,
                                         const float* __restrict__ rpb,
                                         ushort* __restrict__ y,
                                         float* sbias, unsigned int* sP,
                                         int b, int hl, int h, int i) {
  const int NHF = KS / 2, BW = 2 * KS - 1, LK = 64 - KS;
  int tid = threadIdx.x;
  int lane = tid & 63, w = tid >> 6, lo = lane & 15, hi = lane >> 4;

  int wi = i - NHF; wi = wi < 0 ? 0 : (wi > LK ? LK : wi);
  int pi = NHF + ((i < NHF) ? (NHF - i) : 0) + ((i >= 64 - NHF) ? (63 - NHF - i) : 0);

  // stage Toeplitz bias rows (x log2e) + sentinel rows (-1e30 -> exp2 = 0)
  for (int t = tid; t < 2 * KS * BW; t += 256) {
    float v;
    if (t < KS * BW) {
      int ki = t / BW, cb = t - ki * BW;
      v = rpb[((size_t)hl * BW + pi + ki) * BW + cb] * LOG2E;
    } else v = -1e30f;
    sbias[t] = v;
  }
  __syncthreads();

  const ushort* qb = qkvb;
  const ushort* kb = qkvb + (size_t)8 * GM * DH;

  int jbase = 16 * w;
  int j = jbase + lo;                      // this lane's query column
  size_t posQ = (size_t)h * GM + b * 4096 + i * 64 + j;
  short8 aq = *(const short8*)(qb + posQ * DH + hi * 8);   // doubles as B-frag Q^T

  int wj16 = jbase - NHF; wj16 = wj16 < 0 ? 0 : (wj16 > LK ? LK : wj16);
  int cbase = wj16 < 32 ? wj16 : 32;       // 32-wide key band

  int wj = j - NHF; wj = wj < 0 ? 0 : (wj > LK ? LK : wj);

  // per-lane, ki-INDEPENDENT bias byte-offsets (sentinel when c outside window)
  int aoff[8];
#pragma unroll
  for (int t = 0; t < 8; ++t) {
    int c = cbase + (t >> 2) * 16 + hi * 4 + (t & 3);
    int idx = c - j + (KS - 1);
    bool valid = (c >= wj) && (c < wj + KS);
    aoff[t] = valid ? idx * 4 : KS * BW * 4;
  }

  // per-wave P tile [16 rows][16 u32 words], quad-XOR swizzled
  unsigned int* sPw = sP + w * 256;
  unsigned int* pw1 = sPw + lo * 16 + (((hi >> 1)    ) ^ (lo & 3)) * 4 + (hi & 1) * 2;
  unsigned int* pw2 = sPw + lo * 16 + (((hi >> 1) + 2) ^ (lo & 3)) * 4 + (hi & 1) * 2;
  const unsigned int* pr = sPw + lo * 16 + (hi ^ (lo & 3)) * 4;

  f32x4 o0 = {}, o1 = {};
  float den0 = 0.f, den1 = 0.f;
  const f32x4 zero = {};
  const char* sb = (const char*)sbias;

#pragma unroll
  for (int ki = 0; ki < KS; ++ki) {
    const ushort* krow = kb + ((size_t)h * GM + b * 4096 + (wi + ki) * 64 + cbase) * DH;
    short8 bk0 = *(const short8*)(krow + lo * DH + hi * 8);
    short8 bk1 = *(const short8*)(krow + (16 + lo) * DH + hi * 8);
    // swapped: D = S^T tile; lane (lo,hi): query j=jbase+lo, keys hi*4+r (+16)
    f32x4 s0 = __builtin_amdgcn_mfma_f32_16x16x32_bf16(bk0, aq, zero, 0, 0, 0);
    f32x4 s1 = __builtin_amdgcn_mfma_f32_16x16x32_bf16(bk1, aq, zero, 0, 0, 0);

    float p[8];
#pragma unroll
    for (int t = 0; t < 8; ++t) {
      float bv = *(const float*)(sb + (aoff[t] + ki * BW * 4));
      float sv = (t < 4) ? s0[t & 3] : s1[t & 3];
      float e;
      asm("v_exp_f32 %0, %1" : "=v"(e) : "v"(sv + bv));   // 2^x; log2e pre-folded
      p[t] = e;
      if (t & 1) den1 += e; else den0 += e;
    }
    unsigned int u0, u1, u2, u3;
    asm("v_cvt_pk_bf16_f32 %0, %1, %2" : "=v"(u0) : "v"(p[0]), "v"(p[1]));
    asm("v_cvt_pk_bf16_f32 %0, %1, %2" : "=v"(u1) : "v"(p[2]), "v"(p[3]));
    asm("v_cvt_pk_bf16_f32 %0, %1, %2" : "=v"(u2) : "v"(p[4]), "v"(p[5]));
    asm("v_cvt_pk_bf16_f32 %0, %1, %2" : "=v"(u3) : "v"(p[6]), "v"(p[7]));
    *(uint2*)pw1 = make_uint2(u0, u1);
    *(uint2*)pw2 = make_uint2(u2, u3);
    short8 pa = *(const short8*)pr;        // A-frag: P[row j=lo][k=hi*8+e]

    size_t vbase = (size_t)b * 4096 + (wi + ki) * 64 + cbase + hi * 8;
    short8 v0 = *(const short8*)(vt + ((size_t)h * DH + lo) * GM + vbase);
    short8 v1 = *(const short8*)(vt + ((size_t)h * DH + 16 + lo) * GM + vbase);
    o0 = __builtin_amdgcn_mfma_f32_16x16x32_bf16(pa, v0, o0, 0, 0, 0);
    o1 = __builtin_amdgcn_mfma_f32_16x16x32_bf16(pa, v1, o1, 0, 0, 0);
  }

  float den = den0 + den1;
  den += __shfl_xor(den, 16);
  den += __shfl_xor(den, 32);
  float inv = 1.f / den;                   // every lane: inv for query jbase+lo
  float dinv[4];
#pragma unroll
  for (int r = 0; r < 4; ++r) dinv[r] = __shfl(inv, hi * 4 + r);

  size_t ybase = ((size_t)b * 4096 + (size_t)i * 64 + jbase) * 256 + h * DH;
#pragma unroll
  for (int r = 0; r < 4; ++r) {
    int jr = hi * 4 + r;                   // O rows = queries (from PV D-layout)
    y[ybase + (size_t)jr * 256 + lo]      = f2bf(o0[r] * dinv[r]);
    y[ybase + (size_t)jr * 256 + 16 + lo] = f2bf(o1[r] * dinv[r]);
  }
}

__global__ __launch_bounds__(256) void natt_mfma(const ushort* __restrict__ qkvb,
    const ushort* __restrict__ vt, const float* __restrict__ rpb0,
    const float* __restrict__ rpb1, ushort* __restrict__ y) {
  __shared__ float sbias[2 * 13 * 25];
  __shared__ unsigned int sP[4 * 256];
  // XCD-aware decode: all 64 i-blocks of one (b,h) on one XCD; K13/K7 balanced
  int blk = blockIdx.x;
  int xcd = blk & 7, rest = blk >> 3;
  int b = rest >> 6, i = rest & 63;
  int ho = (xcd - b) & 7;
  if (ho < 4) natt_row<13>(qkvb, vt, rpb1, y, sbias, sP, b, ho, ho + 4, i);
  else        natt_row<7> (qkvb, vt, rpb0, y, sbias, sP, b, ho - 4, ho - 4, i);
}

extern "C" void kernel_launch(void* const* d_in, const int* in_sizes, int n_in,
                              void* d_out, int out_size, void* d_ws, size_t ws_size,
                              hipStream_t stream) {
  const float* x      = (const float*)d_in[0];
  const float* w_qkv  = (const float*)d_in[1];
  const float* b_qkv  = (const float*)d_in[2];
  const float* rpb0   = (const float*)d_in[3];
  const float* rpb1   = (const float*)d_in[4];
  const float* w_proj = (const float*)d_in[5];
  const float* b_proj = (const float*)d_in[6];
  float* out = (float*)d_out;

  char* ws = (char*)d_ws;
  ushort* xb   = (ushort*)(ws);                               // 16 MB
  ushort* wqb  = (ushort*)(ws + (16u << 20));                 // 384 KB
  ushort* wpb  = (ushort*)(ws + (16u << 20) + 393216);        // 128 KB
  ushort* qkvb = (ushort*)(ws + (16u << 20) + 524288);        // 48 MB: [24][32768][32] bf16
  ushort* vt   = (ushort*)(ws + (64u << 20) + 524288);        // 16 MB: [8][32][32768] bf16
  ushort* yb   = (ushort*)(ws + (80u << 20) + 524288);        // 16 MB: [32768][256] bf16

  cast_all<<<8448, 256, 0, stream>>>(x, w_qkv, w_proj, xb, wqb, wpb);
  gemm_bt<0><<<1536, 256, 0, stream>>>(xb, wqb, qkvb, nullptr, b_qkv,
                                       32768, 768, 256, 0.17677669529663687f * LOG2E);
  transpose_v<<<1024, 256, 0, stream>>>(qkvb + (size_t)16 * GM * DH, vt);
  natt_mfma<<<4096, 256, 0, stream>>>(qkvb, vt, rpb0, rpb1, yb);
  gemm_bt<1><<<512, 256, 0, stream>>>(yb, wpb, nullptr, out, b_proj,
                                      32768, 256, 256, 1.0f);
}

// Round 5
// 276.831 us; speedup vs baseline: 7.6874x; 1.0125x over previous
//
#include <hip/hip_runtime.h>
#include <hip/hip_bf16.h>

typedef __attribute__((ext_vector_type(8))) short short8;
typedef __attribute__((ext_vector_type(4))) float f32x4;

#define GM 32768   // B*H*W
#define DH 32      // head dim
#define LOG2E 1.4426950408889634f

__device__ __forceinline__ ushort f2bf(float f) {
  unsigned int u = __float_as_uint(f);
  u += 0x7FFFu + ((u >> 16) & 1u);   // round-to-nearest-even
  return (ushort)(u >> 16);
}

// ---- fused cast fp32 -> bf16 for x, w_qkv, w_proj (one launch) ----
__global__ __launch_bounds__(256) void cast_all(
    const float* __restrict__ x, const float* __restrict__ wq, const float* __restrict__ wp,
    ushort* __restrict__ xb, ushort* __restrict__ wqb, ushort* __restrict__ wpb) {
  int bid = blockIdx.x;
  const float* src; ushort* dst; int base;
  if (bid < 8192)      { src = x;  dst = xb;  base = bid * 1024; }
  else if (bid < 8384) { src = wq; dst = wqb; base = (bid - 8192) * 1024; }
  else                 { src = wp; dst = wpb; base = (bid - 8384) * 1024; }
  int idx = base + threadIdx.x * 4;
  float4 t = *(const float4*)(src + idx);
  ushort4 o;
  o.x = f2bf(t.x); o.y = f2bf(t.y); o.z = f2bf(t.z); o.w = f2bf(t.w);
  *(ushort4*)(dst + idx) = o;
}

// ---- bf16 MFMA GEMM: C = A * Bt^T + bias, XCD-swizzled 1D grid ----
// MODE 0: grid 1536 (N=768): qkv epilogue -> bf16 scatter [sel*8+h][pos][32], q scaled
// MODE 1: grid 512  (N=256): proj epilogue -> fp32 row-major
template<int MODE>
__global__ __launch_bounds__(256) void gemm_bt(
    const ushort* __restrict__ A, const ushort* __restrict__ Bt,
    ushort* __restrict__ Cb, float* __restrict__ Cf, const float* __restrict__ bias,
    int M, int N, int K, float scale) {
  const int BM = 128, BN = 128, BK = 64;
  __shared__ int4 sA4[BM * BK / 8];
  __shared__ int4 sB4[BN * BK / 8];

  // XCD-aware decode: same-bm blocks land on one XCD (A-tile L2 reuse)
  int id = blockIdx.x;
  int xcd = id & 7, rest = id >> 3;
  int bm, bn;
  if (MODE == 0) { bm = xcd * 32 + rest / 6;    bn = rest % 6; }
  else           { bm = xcd * 32 + (rest >> 1); bn = rest & 1; }

  int tid = threadIdx.x;
  int lane = tid & 63, wid = tid >> 6;
  int wm = (wid >> 1) * 64, wn = (wid & 1) * 64;
  int lo = lane & 15, hi = lane >> 4;

  f32x4 acc[4][4] = {};

  for (int kt = 0; kt < K; kt += BK) {
    int4 ra[4], rb[4];
#pragma unroll
    for (int i = 0; i < 4; ++i) {
      int cid = tid + i * 256;
      int r = cid >> 3, c = cid & 7;
      ra[i] = *(const int4*)(A  + (size_t)(bm * BM + r) * K + kt + c * 8);
      rb[i] = *(const int4*)(Bt + (size_t)(bn * BN + r) * K + kt + c * 8);
    }
    __syncthreads();
#pragma unroll
    for (int i = 0; i < 4; ++i) {
      int cid = tid + i * 256;
      int r = cid >> 3, c = cid & 7;
      sA4[r * 8 + (c ^ (r & 7))] = ra[i];
      sB4[r * 8 + (c ^ (r & 7))] = rb[i];
    }
    __syncthreads();
#pragma unroll
    for (int ks = 0; ks < 2; ++ks) {
      short8 af[4], bfr[4];
#pragma unroll
      for (int mi = 0; mi < 4; ++mi) {
        int r = wm + mi * 16 + lo, c = ks * 4 + hi;
        af[mi] = ((const short8*)sA4)[r * 8 + (c ^ (r & 7))];
      }
#pragma unroll
      for (int nj = 0; nj < 4; ++nj) {
        int r = wn + nj * 16 + lo, c = ks * 4 + hi;
        bfr[nj] = ((const short8*)sB4)[r * 8 + (c ^ (r & 7))];
      }
#pragma unroll
      for (int mi = 0; mi < 4; ++mi)
#pragma unroll
        for (int nj = 0; nj < 4; ++nj)
          acc[mi][nj] = __builtin_amdgcn_mfma_f32_16x16x32_bf16(
              af[mi], bfr[nj], acc[mi][nj], 0, 0, 0);
    }
  }

#pragma unroll
  for (int mi = 0; mi < 4; ++mi) {
#pragma unroll
    for (int nj = 0; nj < 4; ++nj) {
#pragma unroll
      for (int r = 0; r < 4; ++r) {
        int row = bm * BM + wm + mi * 16 + hi * 4 + r;
        int col = bn * BN + wn + nj * 16 + lo;
        float v = acc[mi][nj][r] + bias[col];
        if (MODE == 0) {
          int sel = col >> 8;
          if (sel == 0) v *= scale;      // q * hd^-0.5 * log2e (exp2 path)
          int hh = (col >> 5) & 7, d = col & 31;
          Cb[((size_t)(sel * 8 + hh) * GM + row) * DH + d] = f2bf(v);
        } else {
          Cf[(size_t)row * N + col] = v;
        }
      }
    }
  }
}

// ---- transpose V: [h][pos][32] bf16 -> vt [h][32][pos] bf16 ----
__global__ __launch_bounds__(256) void transpose_v(const ushort* __restrict__ vsrc,
                                                   ushort* __restrict__ vt) {
  __shared__ ushort tile[DH][264];
  int hb = blockIdx.x >> 7;
  int pb = (blockIdx.x & 127) << 8;
  int t = threadIdx.x;
  const ushort* src = vsrc + ((size_t)hb * GM + pb + t) * DH;
  short8 rbuf[4];
#pragma unroll
  for (int c4 = 0; c4 < 4; ++c4) rbuf[c4] = *(const short8*)(src + c4 * 8);
#pragma unroll
  for (int c4 = 0; c4 < 4; ++c4)
#pragma unroll
    for (int e = 0; e < 8; ++e)
      tile[c4 * 8 + e][t] = (ushort)rbuf[c4][e];
  __syncthreads();
  int d = t >> 3, seg = t & 7;
  ushort* dst = vt + ((size_t)hb * DH + d) * GM + pb + seg * 32;
  const ushort* srow = &tile[d][seg * 32];
#pragma unroll
  for (int c4 = 0; c4 < 4; ++c4)
    *(short8*)(dst + c4 * 8) = *(const short8*)(srow + c4 * 8);
}

// ---- MFMA neighborhood attention v3: two-phase (all QK^T then all PV) ----
// Phase 1: KS*2 independent QK MFMAs + fused exp epilogue -> packed bf16 P in regs.
// Phase 2: P tiles stream through a bank-balanced LDS layout (stride 20 words) -> PV.
template<int KS>
__device__ __forceinline__ void natt_row(const ushort* __restrict__ qkvb,
                                         const ushort* __restrict__ vt,
                                         const float* __restrict__ rpb,
                                         ushort* __restrict__ y,
                                         float* sbias, unsigned int* sP,
                                         int b, int hl, int h, int i) {
  const int NHF = KS / 2, BW = 2 * KS - 1, LK = 64 - KS;
  int tid = threadIdx.x;
  int lane = tid & 63, w = tid >> 6, lo = lane & 15, hi = lane >> 4;

  int wi = i - NHF; wi = wi < 0 ? 0 : (wi > LK ? LK : wi);
  int pi = NHF + ((i < NHF) ? (NHF - i) : 0) + ((i >= 64 - NHF) ? (63 - NHF - i) : 0);

  // stage Toeplitz bias rows (x log2e) + sentinel rows (-1e30 -> exp2 = 0)
  for (int t = tid; t < 2 * KS * BW; t += 256) {
    float v;
    if (t < KS * BW) {
      int ki = t / BW, cb = t - ki * BW;
      v = rpb[((size_t)hl * BW + pi + ki) * BW + cb] * LOG2E;
    } else v = -1e30f;
    sbias[t] = v;
  }
  __syncthreads();

  const ushort* qb = qkvb;
  const ushort* kb = qkvb + (size_t)8 * GM * DH;

  int jbase = 16 * w;
  int j = jbase + lo;                      // this lane's query column
  size_t posQ = (size_t)h * GM + b * 4096 + i * 64 + j;
  short8 aq = *(const short8*)(qb + posQ * DH + hi * 8);   // B-frag Q^T

  int wj16 = jbase - NHF; wj16 = wj16 < 0 ? 0 : (wj16 > LK ? LK : wj16);
  int cbase = wj16 < 32 ? wj16 : 32;       // 32-wide key band

  int wj = j - NHF; wj = wj < 0 ? 0 : (wj > LK ? LK : wj);

  // per-lane, ki-INDEPENDENT bias byte-offsets (sentinel when c outside window)
  int aoff[8];
#pragma unroll
  for (int t = 0; t < 8; ++t) {
    int c = cbase + (t >> 2) * 16 + hi * 4 + (t & 3);
    int idx = c - j + (KS - 1);
    bool valid = (c >= wj) && (c < wj + KS);
    aoff[t] = valid ? idx * 4 : KS * BW * 4;
  }

  // per-wave P tile: 16 rows x 20 u32 words (stride 80B: 16B-aligned, bank-balanced)
  unsigned int* sPw = sP + w * 320;
  unsigned int* pw1 = sPw + lo * 20 + 2 * hi;        // cols hi*4+0..3  -> words 2hi,2hi+1
  unsigned int* pw2 = sPw + lo * 20 + 8 + 2 * hi;    // cols 16+hi*4.. -> words 8+2hi,+1
  const unsigned int* pr = sPw + lo * 20 + 4 * hi;   // b128: cols hi*8..hi*8+7

  const char* sb = (const char*)sbias;
  const ushort* kband = kb + ((size_t)h * GM + b * 4096 + (size_t)wi * 64 + cbase) * DH;

  uint2 pk1[KS], pk2[KS];
  float den0 = 0.f, den1 = 0.f;
  const f32x4 zero = {};

  // ---- Phase 1: all QK^T + exp, P packed into registers ----
#pragma unroll
  for (int ki = 0; ki < KS; ++ki) {
    const ushort* krow = kband + (size_t)ki * 64 * DH;
    short8 bk0 = *(const short8*)(krow + lo * DH + hi * 8);
    short8 bk1 = *(const short8*)(krow + (16 + lo) * DH + hi * 8);
    f32x4 s0 = __builtin_amdgcn_mfma_f32_16x16x32_bf16(bk0, aq, zero, 0, 0, 0);
    f32x4 s1 = __builtin_amdgcn_mfma_f32_16x16x32_bf16(bk1, aq, zero, 0, 0, 0);

    float p[8];
#pragma unroll
    for (int t = 0; t < 8; ++t) {
      float bv = *(const float*)(sb + (aoff[t] + ki * BW * 4));
      float sv = (t < 4) ? s0[t & 3] : s1[t & 3];
      float e;
      asm("v_exp_f32 %0, %1" : "=v"(e) : "v"(sv + bv));   // 2^x; log2e pre-folded
      p[t] = e;
      if (t & 1) den1 += e; else den0 += e;
    }
    unsigned int u0, u1, u2, u3;
    asm("v_cvt_pk_bf16_f32 %0, %1, %2" : "=v"(u0) : "v"(p[0]), "v"(p[1]));
    asm("v_cvt_pk_bf16_f32 %0, %1, %2" : "=v"(u1) : "v"(p[2]), "v"(p[3]));
    asm("v_cvt_pk_bf16_f32 %0, %1, %2" : "=v"(u2) : "v"(p[4]), "v"(p[5]));
    asm("v_cvt_pk_bf16_f32 %0, %1, %2" : "=v"(u3) : "v"(p[6]), "v"(p[7]));
    pk1[ki] = make_uint2(u0, u1);
    pk2[ki] = make_uint2(u2, u3);
  }

  // ---- Phase 2: LDS round-trip (pipelined on in-order DS pipe) + PV ----
  f32x4 o0 = {}, o1 = {};
#pragma unroll
  for (int ki = 0; ki < KS; ++ki) {
    size_t vbase = (size_t)b * 4096 + (size_t)(wi + ki) * 64 + cbase + hi * 8;
    short8 v0 = *(const short8*)(vt + ((size_t)h * DH + lo) * GM + vbase);
    short8 v1 = *(const short8*)(vt + ((size_t)h * DH + 16 + lo) * GM + vbase);
    *(uint2*)pw1 = pk1[ki];
    *(uint2*)pw2 = pk2[ki];
    __builtin_amdgcn_sched_barrier(0);     // pin write -> read order (cross-lane via LDS)
    short8 pa = *(const short8*)pr;        // A-frag: P[row j=lo][k=hi*8+e]
    o0 = __builtin_amdgcn_mfma_f32_16x16x32_bf16(pa, v0, o0, 0, 0, 0);
    o1 = __builtin_amdgcn_mfma_f32_16x16x32_bf16(pa, v1, o1, 0, 0, 0);
  }

  float den = den0 + den1;
  den += __shfl_xor(den, 16);
  den += __shfl_xor(den, 32);
  float inv = 1.f / den;                   // every lane: inv for query jbase+lo
  float dinv[4];
#pragma unroll
  for (int r = 0; r < 4; ++r) dinv[r] = __shfl(inv, hi * 4 + r);

  size_t ybase = ((size_t)b * 4096 + (size_t)i * 64 + jbase) * 256 + h * DH;
#pragma unroll
  for (int r = 0; r < 4; ++r) {
    int jr = hi * 4 + r;                   // O rows = queries (from PV D-layout)
    y[ybase + (size_t)jr * 256 + lo]      = f2bf(o0[r] * dinv[r]);
    y[ybase + (size_t)jr * 256 + 16 + lo] = f2bf(o1[r] * dinv[r]);
  }
}

__global__ __launch_bounds__(256) void natt_mfma(const ushort* __restrict__ qkvb,
    const ushort* __restrict__ vt, const float* __restrict__ rpb0,
    const float* __restrict__ rpb1, ushort* __restrict__ y) {
  __shared__ float sbias[2 * 13 * 25];
  __shared__ unsigned int sP[4 * 320];
  // XCD-aware decode: all 64 i-blocks of one (b,h) on one XCD; K13/K7 balanced
  int blk = blockIdx.x;
  int xcd = blk & 7, rest = blk >> 3;
  int b = rest >> 6, i = rest & 63;
  int ho = (xcd - b) & 7;
  if (ho < 4) natt_row<13>(qkvb, vt, rpb1, y, sbias, sP, b, ho, ho + 4, i);
  else        natt_row<7> (qkvb, vt, rpb0, y, sbias, sP, b, ho - 4, ho - 4, i);
}

extern "C" void kernel_launch(void* const* d_in, const int* in_sizes, int n_in,
                              void* d_out, int out_size, void* d_ws, size_t ws_size,
                              hipStream_t stream) {
  const float* x      = (const float*)d_in[0];
  const float* w_qkv  = (const float*)d_in[1];
  const float* b_qkv  = (const float*)d_in[2];
  const float* rpb0   = (const float*)d_in[3];
  const float* rpb1   = (const float*)d_in[4];
  const float* w_proj = (const float*)d_in[5];
  const float* b_proj = (const float*)d_in[6];
  float* out = (float*)d_out;

  char* ws = (char*)d_ws;
  ushort* xb   = (ushort*)(ws);                               // 16 MB
  ushort* wqb  = (ushort*)(ws + (16u << 20));                 // 384 KB
  ushort* wpb  = (ushort*)(ws + (16u << 20) + 393216);        // 128 KB
  ushort* qkvb = (ushort*)(ws + (16u << 20) + 524288);        // 48 MB: [24][32768][32] bf16
  ushort* vt   = (ushort*)(ws + (64u << 20) + 524288);        // 16 MB: [8][32][32768] bf16
  ushort* yb   = (ushort*)(ws + (80u << 20) + 524288);        // 16 MB: [32768][256] bf16

  cast_all<<<8448, 256, 0, stream>>>(x, w_qkv, w_proj, xb, wqb, wpb);
  gemm_bt<0><<<1536, 256, 0, stream>>>(xb, wqb, qkvb, nullptr, b_qkv,
                                       32768, 768, 256, 0.17677669529663687f * LOG2E);
  transpose_v<<<1024, 256, 0, stream>>>(qkvb + (size_t)16 * GM * DH, vt);
  natt_mfma<<<4096, 256, 0, stream>>>(qkvb, vt, rpb0, rpb1, yb);
  gemm_bt<1><<<512, 256, 0, stream>>>(yb, wpb, nullptr, out, b_proj,
                                      32768, 256, 256, 1.0f);
}

// Round 6
// 234.576 us; speedup vs baseline: 9.0722x; 1.1801x over previous
//
#include <hip/hip_runtime.h>
#include <hip/hip_bf16.h>

typedef __attribute__((ext_vector_type(8))) short short8;
typedef __attribute__((ext_vector_type(4))) float f32x4;

#define GM 32768   // B*H*W
#define DH 32      // head dim
#define LOG2E 1.4426950408889634f

__device__ __forceinline__ ushort f2bf(float f) {
  unsigned int u = __float_as_uint(f);
  u += 0x7FFFu + ((u >> 16) & 1u);   // round-to-nearest-even
  return (ushort)(u >> 16);
}
__device__ __forceinline__ unsigned int cvtpk(float a, float b) {
  unsigned int r;
  asm("v_cvt_pk_bf16_f32 %0, %1, %2" : "=v"(r) : "v"(a), "v"(b));
  return r;
}

// ---- bf16 MFMA GEMM with fused fp32->bf16 cast of inputs ----
// MODE 0: A=x fp32, B=w_qkv fp32; epilogue -> bf16 [sel*8+h][pos][32] via LDS
//         re-layout (coalesced 16B stores); q cols scaled.
// MODE 1: A=yb bf16, B=w_proj fp32; epilogue -> fp32 row-major + bias.
template<int MODE>
__global__ __launch_bounds__(256) void gemm_bt(
    const float* __restrict__ Af, const ushort* __restrict__ Ab,
    const float* __restrict__ Bf,
    ushort* __restrict__ Cb, float* __restrict__ Cf, const float* __restrict__ bias,
    float scale) {
  const int BM = 128, BN = 128, BK = 64, K = 256;
  __shared__ int4 sA4[BM * BK / 8];
  __shared__ int4 sB4[BN * BK / 8];

  // XCD-aware decode: same-bm blocks land on one XCD (A-tile L2 reuse)
  int id = blockIdx.x;
  int xcd = id & 7, rest = id >> 3;
  int bm, bn;
  if (MODE == 0) { bm = xcd * 32 + rest / 6;    bn = rest % 6; }
  else           { bm = xcd * 32 + (rest >> 1); bn = rest & 1; }

  int tid = threadIdx.x;
  int lane = tid & 63, wid = tid >> 6;
  int wm = (wid >> 1) * 64, wn = (wid & 1) * 64;
  int lo = lane & 15, hi = lane >> 4;

  f32x4 acc[4][4] = {};

  for (int kt = 0; kt < K; kt += BK) {
    int4 ra[4], rb[4];
#pragma unroll
    for (int i = 0; i < 4; ++i) {
      int cid = tid + i * 256;
      int r = cid >> 3, c = cid & 7;
      if (MODE == 0) {
        const float* p = Af + (size_t)(bm * BM + r) * K + kt + c * 8;
        float4 t0 = *(const float4*)p, t1 = *(const float4*)(p + 4);
        ra[i] = make_int4(cvtpk(t0.x, t0.y), cvtpk(t0.z, t0.w),
                          cvtpk(t1.x, t1.y), cvtpk(t1.z, t1.w));
      } else {
        ra[i] = *(const int4*)(Ab + (size_t)(bm * BM + r) * K + kt + c * 8);
      }
      const float* q = Bf + (size_t)(bn * BN + r) * K + kt + c * 8;
      float4 s0 = *(const float4*)q, s1 = *(const float4*)(q + 4);
      rb[i] = make_int4(cvtpk(s0.x, s0.y), cvtpk(s0.z, s0.w),
                        cvtpk(s1.x, s1.y), cvtpk(s1.z, s1.w));
    }
    __syncthreads();
#pragma unroll
    for (int i = 0; i < 4; ++i) {
      int cid = tid + i * 256;
      int r = cid >> 3, c = cid & 7;
      sA4[r * 8 + (c ^ (r & 7))] = ra[i];
      sB4[r * 8 + (c ^ (r & 7))] = rb[i];
    }
    __syncthreads();
#pragma unroll
    for (int ks = 0; ks < 2; ++ks) {
      short8 af[4], bfr[4];
#pragma unroll
      for (int mi = 0; mi < 4; ++mi) {
        int r = wm + mi * 16 + lo, c = ks * 4 + hi;
        af[mi] = ((const short8*)sA4)[r * 8 + (c ^ (r & 7))];
      }
#pragma unroll
      for (int nj = 0; nj < 4; ++nj) {
        int r = wn + nj * 16 + lo, c = ks * 4 + hi;
        bfr[nj] = ((const short8*)sB4)[r * 8 + (c ^ (r & 7))];
      }
#pragma unroll
      for (int mi = 0; mi < 4; ++mi)
#pragma unroll
        for (int nj = 0; nj < 4; ++nj)
          acc[mi][nj] = __builtin_amdgcn_mfma_f32_16x16x32_bf16(
              af[mi], bfr[nj], acc[mi][nj], 0, 0, 0);
    }
  }

  if (MODE == 0) {
    // re-layout C tile through LDS -> fully coalesced 16B stores
    float sc = (bn < 2) ? scale : 1.0f;
    __syncthreads();
    ushort* sC = (ushort*)sA4;           // [128 rows][16 chunks of 8, XOR-swizzled]
#pragma unroll
    for (int mi = 0; mi < 4; ++mi)
#pragma unroll
      for (int nj = 0; nj < 4; ++nj)
#pragma unroll
        for (int r = 0; r < 4; ++r) {
          int row = wm + mi * 16 + hi * 4 + r;
          int col = wn + nj * 16 + lo;
          float v = (acc[mi][nj][r] + bias[bn * BN + col]) * sc;
          sC[row * 128 + (((col >> 3) ^ (row & 15)) << 3) + (col & 7)] = f2bf(v);
        }
    __syncthreads();
    int sel = bn >> 1;
    size_t base0 = ((size_t)(sel * 8 + (bn & 1) * 4) * GM + (size_t)bm * BM) * DH;
#pragma unroll
    for (int p8 = 0; p8 < 8; ++p8) {
      int o = p8 * 256 + tid;
      int hh = o >> 9, row = (o >> 2) & 127, q = o & 3;
      int4 val = *(const int4*)(sC + row * 128 + (((hh * 4 + q) ^ (row & 15)) << 3));
      *(int4*)(Cb + base0 + (size_t)hh * GM * DH + row * DH + q * 8) = val;
    }
  } else {
#pragma unroll
    for (int mi = 0; mi < 4; ++mi)
#pragma unroll
      for (int nj = 0; nj < 4; ++nj)
#pragma unroll
        for (int r = 0; r < 4; ++r) {
          int row = bm * BM + wm + mi * 16 + hi * 4 + r;
          int col = bn * BN + wn + nj * 16 + lo;
          Cf[(size_t)row * 256 + col] = acc[mi][nj][r] + bias[col];
        }
  }
}

// ---- transpose V: [h][pos][32] bf16 -> vt [h][32][pos] bf16 ----
__global__ __launch_bounds__(256) void transpose_v(const ushort* __restrict__ vsrc,
                                                   ushort* __restrict__ vt) {
  __shared__ ushort tile[DH][264];
  int hb = blockIdx.x >> 7;
  int pb = (blockIdx.x & 127) << 8;
  int t = threadIdx.x;
  const ushort* src = vsrc + ((size_t)hb * GM + pb + t) * DH;
  short8 rbuf[4];
#pragma unroll
  for (int c4 = 0; c4 < 4; ++c4) rbuf[c4] = *(const short8*)(src + c4 * 8);
#pragma unroll
  for (int c4 = 0; c4 < 4; ++c4)
#pragma unroll
    for (int e = 0; e < 8; ++e)
      tile[c4 * 8 + e][t] = (ushort)rbuf[c4][e];
  __syncthreads();
  int d = t >> 3, seg = t & 7;
  ushort* dst = vt + ((size_t)hb * DH + d) * GM + pb + seg * 32;
  const ushort* srow = &tile[d][seg * 32];
#pragma unroll
  for (int c4 = 0; c4 < 4; ++c4)
    *(short8*)(dst + c4 * 8) = *(const short8*)(srow + c4 * 8);
}

// ---- MFMA neighborhood attention v4: depth-2 prefetch + skewed PV ----
template<int KS>
__device__ __forceinline__ void natt_row(const ushort* __restrict__ qkvb,
                                         const ushort* __restrict__ vt,
                                         const float* __restrict__ rpb,
                                         ushort* __restrict__ y,
                                         float* sbias, unsigned int* sP,
                                         int b, int hl, int h, int i) {
  const int NHF = KS / 2, BW = 2 * KS - 1, LK = 64 - KS;
  int tid = threadIdx.x;
  int lane = tid & 63, w = tid >> 6, lo = lane & 15, hi = lane >> 4;

  int wi = i - NHF; wi = wi < 0 ? 0 : (wi > LK ? LK : wi);
  int pi = NHF + ((i < NHF) ? (NHF - i) : 0) + ((i >= 64 - NHF) ? (63 - NHF - i) : 0);

  // stage Toeplitz bias rows (x log2e) + sentinel rows (-1e30 -> exp2 = 0)
  for (int t = tid; t < 2 * KS * BW; t += 256) {
    float v;
    if (t < KS * BW) {
      int ki = t / BW, cb = t - ki * BW;
      v = rpb[((size_t)hl * BW + pi + ki) * BW + cb] * LOG2E;
    } else v = -1e30f;
    sbias[t] = v;
  }
  __syncthreads();

  const ushort* qb = qkvb;
  const ushort* kb = qkvb + (size_t)8 * GM * DH;

  int jbase = 16 * w;
  int j = jbase + lo;
  size_t posQ = (size_t)h * GM + b * 4096 + i * 64 + j;
  short8 aq = *(const short8*)(qb + posQ * DH + hi * 8);   // B-frag Q^T

  int wj16 = jbase - NHF; wj16 = wj16 < 0 ? 0 : (wj16 > LK ? LK : wj16);
  int cbase = wj16 < 32 ? wj16 : 32;       // 32-wide key band
  int wj = j - NHF; wj = wj < 0 ? 0 : (wj > LK ? LK : wj);

  // per-lane, ki-independent bias byte-offsets (sentinel when outside window)
  int aoff[8];
#pragma unroll
  for (int t = 0; t < 8; ++t) {
    int c = cbase + (t >> 2) * 16 + hi * 4 + (t & 3);
    int idx = c - j + (KS - 1);
    bool valid = (c >= wj) && (c < wj + KS);
    aoff[t] = valid ? idx * 4 : KS * BW * 4;
  }

  // double-buffered per-wave P tile: 2 slots x [16 rows][20 words]
  unsigned int* sPw = sP + w * 640;
  unsigned int* pw1 = sPw + lo * 20 + 2 * hi;
  unsigned int* pw2 = sPw + lo * 20 + 8 + 2 * hi;
  const unsigned int* pr = sPw + lo * 20 + 4 * hi;

  const char* sb = (const char*)sbias;
  const ushort* kband = kb + ((size_t)h * GM + b * 4096 + (size_t)wi * 64 + cbase) * DH;
  const ushort* vrow0 = vt + ((size_t)h * DH + lo) * GM
                        + ((size_t)b * 4096 + (size_t)wi * 64 + cbase + hi * 8);
  const ushort* vrow1 = vrow0 + (size_t)16 * GM;

#define LOADK(KI, F0, F1) { const ushort* kr_ = kband + (KI) * 64 * DH; \
    F0 = *(const short8*)(kr_ + lo * DH + hi * 8); \
    F1 = *(const short8*)(kr_ + (16 + lo) * DH + hi * 8); }
#define LOADV(KI, F0, F1) { \
    F0 = *(const short8*)(vrow0 + (KI) * 64); \
    F1 = *(const short8*)(vrow1 + (KI) * 64); }

  const f32x4 zero = {};
  f32x4 o0 = {}, o1 = {};
  float den0 = 0.f, den1 = 0.f;

  short8 ck0, ck1, cv0, cv1, nk0, nk1, nv0, nv1, vp0, vp1;
  LOADK(0, ck0, ck1);
  LOADV(0, cv0, cv1);

#pragma unroll
  for (int ki = 0; ki < KS; ++ki) {
    // 1. prefetch next K/V (one full iteration of latency cover)
    if (ki + 1 < KS) {
      LOADK(ki + 1, nk0, nk1);
      LOADV(ki + 1, nv0, nv1);
    }
    // 2. QK^T(ki): lane (lo,hi) -> query lo, keys hi*4+r (+16)
    f32x4 s0 = __builtin_amdgcn_mfma_f32_16x16x32_bf16(ck0, aq, zero, 0, 0, 0);
    f32x4 s1 = __builtin_amdgcn_mfma_f32_16x16x32_bf16(ck1, aq, zero, 0, 0, 0);
    // 3. bias + exp2
    float p[8];
#pragma unroll
    for (int t = 0; t < 8; ++t) {
      float bv = *(const float*)(sb + (aoff[t] + ki * BW * 4));
      float sv = (t < 4) ? s0[t & 3] : s1[t & 3];
      float e;
      asm("v_exp_f32 %0, %1" : "=v"(e) : "v"(sv + bv));
      p[t] = e;
      if (t & 1) den1 += e; else den0 += e;
    }
    // 4. pack + write P(ki) to slot ki&1
    unsigned int u0 = cvtpk(p[0], p[1]), u1 = cvtpk(p[2], p[3]);
    unsigned int u2 = cvtpk(p[4], p[5]), u3 = cvtpk(p[6], p[7]);
    *(uint2*)(pw1 + (ki & 1) * 320) = make_uint2(u0, u1);
    *(uint2*)(pw2 + (ki & 1) * 320) = make_uint2(u2, u3);
    // 5. PV(ki-1) from the other slot (write->read gap filled by steps 1-4)
    if (ki > 0) {
      short8 pa = *(const short8*)(pr + ((ki - 1) & 1) * 320);
      o0 = __builtin_amdgcn_mfma_f32_16x16x32_bf16(pa, vp0, o0, 0, 0, 0);
      o1 = __builtin_amdgcn_mfma_f32_16x16x32_bf16(pa, vp1, o1, 0, 0, 0);
    }
    // rotate
    vp0 = cv0; vp1 = cv1;
    cv0 = nv0; cv1 = nv1;
    ck0 = nk0; ck1 = nk1;
  }
  {  // drain PV(KS-1)
    short8 pa = *(const short8*)(pr + ((KS - 1) & 1) * 320);
    o0 = __builtin_amdgcn_mfma_f32_16x16x32_bf16(pa, vp0, o0, 0, 0, 0);
    o1 = __builtin_amdgcn_mfma_f32_16x16x32_bf16(pa, vp1, o1, 0, 0, 0);
  }
#undef LOADK
#undef LOADV

  float den = den0 + den1;
  den += __shfl_xor(den, 16);
  den += __shfl_xor(den, 32);
  float inv = 1.f / den;
  float dinv[4];
#pragma unroll
  for (int r = 0; r < 4; ++r) dinv[r] = __shfl(inv, hi * 4 + r);

  size_t ybase = ((size_t)b * 4096 + (size_t)i * 64 + jbase) * 256 + h * DH;
#pragma unroll
  for (int r = 0; r < 4; ++r) {
    int jr = hi * 4 + r;
    y[ybase + (size_t)jr * 256 + lo]      = f2bf(o0[r] * dinv[r]);
    y[ybase + (size_t)jr * 256 + 16 + lo] = f2bf(o1[r] * dinv[r]);
  }
}

__global__ __launch_bounds__(256) void natt_mfma(const ushort* __restrict__ qkvb,
    const ushort* __restrict__ vt, const float* __restrict__ rpb0,
    const float* __restrict__ rpb1, ushort* __restrict__ y) {
  __shared__ float sbias[2 * 13 * 25];
  __shared__ unsigned int sP[4 * 640];
  int blk = blockIdx.x;
  int xcd = blk & 7, rest = blk >> 3;
  int b = rest >> 6, i = rest & 63;
  int ho = (xcd - b) & 7;
  if (ho < 4) natt_row<13>(qkvb, vt, rpb1, y, sbias, sP, b, ho, ho + 4, i);
  else        natt_row<7> (qkvb, vt, rpb0, y, sbias, sP, b, ho - 4, ho - 4, i);
}

extern "C" void kernel_launch(void* const* d_in, const int* in_sizes, int n_in,
                              void* d_out, int out_size, void* d_ws, size_t ws_size,
                              hipStream_t stream) {
  const float* x      = (const float*)d_in[0];
  const float* w_qkv  = (const float*)d_in[1];
  const float* b_qkv  = (const float*)d_in[2];
  const float* rpb0   = (const float*)d_in[3];
  const float* rpb1   = (const float*)d_in[4];
  const float* w_proj = (const float*)d_in[5];
  const float* b_proj = (const float*)d_in[6];
  float* out = (float*)d_out;

  char* ws = (char*)d_ws;
  ushort* qkvb = (ushort*)(ws);                    // 48 MB: [24][32768][32] bf16
  ushort* vt   = (ushort*)(ws + (48u << 20));      // 16 MB: [8][32][32768] bf16
  ushort* yb   = (ushort*)(ws + (64u << 20));      // 16 MB: [32768][256] bf16

  gemm_bt<0><<<1536, 256, 0, stream>>>(x, nullptr, w_qkv, qkvb, nullptr, b_qkv,
                                       0.17677669529663687f * LOG2E);
  transpose_v<<<1024, 256, 0, stream>>>(qkvb + (size_t)16 * GM * DH, vt);
  natt_mfma<<<4096, 256, 0, stream>>>(qkvb, vt, rpb0, rpb1, yb);
  gemm_bt<1><<<512, 256, 0, stream>>>(nullptr, yb, w_proj, nullptr, out, b_proj, 1.0f);
}

// Round 7
// 198.388 us; speedup vs baseline: 10.7270x; 1.1824x over previous
//
#include <hip/hip_runtime.h>
#include <hip/hip_bf16.h>

typedef __attribute__((ext_vector_type(8))) short short8;
typedef __attribute__((ext_vector_type(4))) float f32x4;

#define GM 32768   // B*H*W
#define DH 32      // head dim
#define LOG2E 1.4426950408889634f

__device__ __forceinline__ ushort f2bf(float f) {
  unsigned int u = __float_as_uint(f);
  u += 0x7FFFu + ((u >> 16) & 1u);   // round-to-nearest-even
  return (ushort)(u >> 16);
}
__device__ __forceinline__ unsigned int cvtpk(float a, float b) {
  unsigned int r;
  asm("v_cvt_pk_bf16_f32 %0, %1, %2" : "=v"(r) : "v"(a), "v"(b));
  return r;
}

// ---- bf16 MFMA GEMM with fused fp32->bf16 cast of inputs ----
// MODE 0: A=x fp32, B=w_qkv fp32; epilogue: q/k -> bf16 [sel*8+h][pos][32]
//         (coalesced via LDS); V -> TRANSPOSED vt[h][d][pos] (fused transpose).
// MODE 1: A=yb bf16, B=w_proj fp32; epilogue -> fp32 row-major + bias.
template<int MODE>
__global__ __launch_bounds__(256) void gemm_bt(
    const float* __restrict__ Af, const ushort* __restrict__ Ab,
    const float* __restrict__ Bf,
    ushort* __restrict__ Cb, ushort* __restrict__ Vt,
    float* __restrict__ Cf, const float* __restrict__ bias, float scale) {
  const int BM = 128, BN = 128, BK = 64, K = 256;
  __shared__ int4 sAB[2 * BM * BK / 8];    // 32 KB: A tile + B tile (also C staging)
  int4* sA4 = sAB;
  int4* sB4 = sAB + BM * BK / 8;

  // XCD-aware decode: same-bm blocks land on one XCD (A-tile L2 reuse)
  int id = blockIdx.x;
  int xcd = id & 7, rest = id >> 3;
  int bm, bn;
  if (MODE == 0) { bm = xcd * 32 + rest / 6;    bn = rest % 6; }
  else           { bm = xcd * 32 + (rest >> 1); bn = rest & 1; }

  int tid = threadIdx.x;
  int lane = tid & 63, wid = tid >> 6;
  int wm = (wid >> 1) * 64, wn = (wid & 1) * 64;
  int lo = lane & 15, hi = lane >> 4;

  f32x4 acc[4][4] = {};

  for (int kt = 0; kt < K; kt += BK) {
    int4 ra[4], rb[4];
#pragma unroll
    for (int i = 0; i < 4; ++i) {
      int cid = tid + i * 256;
      int r = cid >> 3, c = cid & 7;
      if (MODE == 0) {
        const float* p = Af + (size_t)(bm * BM + r) * K + kt + c * 8;
        float4 t0 = *(const float4*)p, t1 = *(const float4*)(p + 4);
        ra[i] = make_int4(cvtpk(t0.x, t0.y), cvtpk(t0.z, t0.w),
                          cvtpk(t1.x, t1.y), cvtpk(t1.z, t1.w));
      } else {
        ra[i] = *(const int4*)(Ab + (size_t)(bm * BM + r) * K + kt + c * 8);
      }
      const float* q = Bf + (size_t)(bn * BN + r) * K + kt + c * 8;
      float4 s0 = *(const float4*)q, s1 = *(const float4*)(q + 4);
      rb[i] = make_int4(cvtpk(s0.x, s0.y), cvtpk(s0.z, s0.w),
                        cvtpk(s1.x, s1.y), cvtpk(s1.z, s1.w));
    }
    __syncthreads();
#pragma unroll
    for (int i = 0; i < 4; ++i) {
      int cid = tid + i * 256;
      int r = cid >> 3, c = cid & 7;
      sA4[r * 8 + (c ^ (r & 7))] = ra[i];
      sB4[r * 8 + (c ^ (r & 7))] = rb[i];
    }
    __syncthreads();
#pragma unroll
    for (int ks = 0; ks < 2; ++ks) {
      short8 af[4], bfr[4];
#pragma unroll
      for (int mi = 0; mi < 4; ++mi) {
        int r = wm + mi * 16 + lo, c = ks * 4 + hi;
        af[mi] = ((const short8*)sA4)[r * 8 + (c ^ (r & 7))];
      }
#pragma unroll
      for (int nj = 0; nj < 4; ++nj) {
        int r = wn + nj * 16 + lo, c = ks * 4 + hi;
        bfr[nj] = ((const short8*)sB4)[r * 8 + (c ^ (r & 7))];
      }
#pragma unroll
      for (int mi = 0; mi < 4; ++mi)
#pragma unroll
        for (int nj = 0; nj < 4; ++nj)
          acc[mi][nj] = __builtin_amdgcn_mfma_f32_16x16x32_bf16(
              af[mi], bfr[nj], acc[mi][nj], 0, 0, 0);
    }
  }

  if (MODE == 0) {
    float sc = (bn < 2) ? scale : 1.0f;
    __syncthreads();
    ushort* sC = (ushort*)sAB;           // [128 rows][16 chunks of 8, XOR-swizzled]
#pragma unroll
    for (int mi = 0; mi < 4; ++mi)
#pragma unroll
      for (int nj = 0; nj < 4; ++nj)
#pragma unroll
        for (int r = 0; r < 4; ++r) {
          int row = wm + mi * 16 + hi * 4 + r;
          int col = wn + nj * 16 + lo;
          float v = (acc[mi][nj][r] + bias[bn * BN + col]) * sc;
          sC[row * 128 + (((col >> 3) ^ (row & 15)) << 3) + (col & 7)] = f2bf(v);
        }
    __syncthreads();
    if (bn < 4) {
      // q/k: coalesced 16B stores to [sel*8+h][pos][32]
      int sel = bn >> 1;
      size_t base0 = ((size_t)(sel * 8 + (bn & 1) * 4) * GM + (size_t)bm * BM) * DH;
#pragma unroll
      for (int p8 = 0; p8 < 8; ++p8) {
        int o = p8 * 256 + tid;
        int hh = o >> 9, row = (o >> 2) & 127, q = o & 3;
        int4 val = *(const int4*)(sC + row * 128 + (((hh * 4 + q) ^ (row & 15)) << 3));
        *(int4*)(Cb + base0 + (size_t)hh * GM * DH + row * DH + q * 8) = val;
      }
    } else {
      // V: fused transpose -> vt[h*32+d][pos], coalesced 16B stores
      int hb32 = (bn - 4) * 128;         // vt row base = (hbase*32 + col)
#pragma unroll
      for (int p8 = 0; p8 < 8; ++p8) {
        int o = p8 * 256 + tid;
        int col = o >> 4, chunk = o & 15;
        int4 val;
        ushort* vp = (ushort*)&val;
#pragma unroll
        for (int e = 0; e < 8; ++e) {
          int row = chunk * 8 + e;
          vp[e] = sC[row * 128 + (((col >> 3) ^ (row & 15)) << 3) + (col & 7)];
        }
        *(int4*)(Vt + (size_t)(hb32 + col) * GM + (size_t)bm * BM + chunk * 8) = val;
      }
    }
  } else {
#pragma unroll
    for (int mi = 0; mi < 4; ++mi)
#pragma unroll
      for (int nj = 0; nj < 4; ++nj)
#pragma unroll
        for (int r = 0; r < 4; ++r) {
          int row = bm * BM + wm + mi * 16 + hi * 4 + r;
          int col = bn * BN + wn + nj * 16 + lo;
          Cf[(size_t)row * 256 + col] = acc[mi][nj][r] + bias[col];
        }
  }
}

// ---- MFMA neighborhood attention v5: one wave = TWO adjacent i-rows ----
// Rows i0,i0+1 share every K/V load (window shift d in {0,1}); two independent
// QK->exp->PV chains interleave to fill latency. Skewed PV (ki-1) as before.
template<int KS>
__device__ __forceinline__ void natt_pair(const ushort* __restrict__ qkvb,
                                          const ushort* __restrict__ vt,
                                          const float* __restrict__ rpb,
                                          ushort* __restrict__ y,
                                          float* sbias, unsigned int* sP,
                                          int b, int hl, int h, int i0) {
  const int NHF = KS / 2, BW = 2 * KS - 1, LK = 64 - KS, TS = KS * BW;
  int tid = threadIdx.x;
  int lane = tid & 63, w = tid >> 6, lo = lane & 15, hi = lane >> 4;
  int i1 = i0 + 1;

  int wi0 = i0 - NHF; wi0 = wi0 < 0 ? 0 : (wi0 > LK ? LK : wi0);
  int wi1 = i1 - NHF; wi1 = wi1 < 0 ? 0 : (wi1 > LK ? LK : wi1);
  int d = wi1 - wi0;   // 0 or 1, wave-uniform
  int pi0 = NHF + ((i0 < NHF) ? (NHF - i0) : 0) + ((i0 >= 64 - NHF) ? (63 - NHF - i0) : 0);
  int pi1 = NHF + ((i1 < NHF) ? (NHF - i1) : 0) + ((i1 >= 64 - NHF) ? (63 - NHF - i1) : 0);

  // stage bias tables T0(pi0), T1(pi1) (x log2e) + sentinel region [2TS,4TS)
  for (int t = tid; t < 4 * TS; t += 256) {
    float v = -1e30f;
    if (t < TS) {
      int ki = t / BW, cb = t - ki * BW;
      v = rpb[((size_t)hl * BW + pi0 + ki) * BW + cb] * LOG2E;
    } else if (t < 2 * TS) {
      int tt = t - TS, ki = tt / BW, cb = tt - ki * BW;
      v = rpb[((size_t)hl * BW + pi1 + ki) * BW + cb] * LOG2E;
    }
    sbias[t] = v;
  }
  __syncthreads();

  const ushort* qb = qkvb;
  const ushort* kb = qkvb + (size_t)8 * GM * DH;

  int jbase = 16 * w;
  int j = jbase + lo;
  size_t posQ0 = (size_t)h * GM + b * 4096 + i0 * 64 + j;
  short8 aq0 = *(const short8*)(qb + posQ0 * DH + hi * 8);
  short8 aq1 = *(const short8*)(qb + (posQ0 + 64) * DH + hi * 8);

  int wj16 = jbase - NHF; wj16 = wj16 < 0 ? 0 : (wj16 > LK ? LK : wj16);
  int cbase = wj16 < 32 ? wj16 : 32;       // 32-wide key band (row-independent)
  int wj = j - NHF; wj = wj < 0 ? 0 : (wj > LK ? LK : wj);

  // per-lane bias byte-offsets: row-independent (depend only on j geometry)
  int aoff[8];
#pragma unroll
  for (int t = 0; t < 8; ++t) {
    int c = cbase + (t >> 2) * 16 + hi * 4 + (t & 3);
    int idx = c - j + (KS - 1);
    bool valid = (c >= wj) && (c < wj + KS);
    aoff[t] = valid ? idx * 4 : 2 * TS * 4;
  }
  int rbase1 = (TS - d * BW) * 4;          // row1 table base (ki1 = t - d)

  // P tiles: per (wave,row): 2 slots x [16 rows][20 words] (stride 80B)
  unsigned int* base0 = sP + (w * 4) * 320;
  unsigned int* base1 = sP + (w * 4 + 2) * 320;
  int pwo1 = lo * 20 + 2 * hi, pwo2 = lo * 20 + 8 + 2 * hi, pro = lo * 20 + 4 * hi;

  const char* sb = (const char*)sbias;
  const ushort* kband = kb + ((size_t)h * GM + b * 4096 + (size_t)wi0 * 64 + cbase) * DH;
  const ushort* vrow0 = vt + ((size_t)h * DH + lo) * GM
                        + ((size_t)b * 4096 + (size_t)wi0 * 64 + cbase + hi * 8);
  const ushort* vrow1 = vrow0 + (size_t)16 * GM;

#define LOADK(KI, F0, F1) { const ushort* kr_ = kband + (KI) * 64 * DH; \
    F0 = *(const short8*)(kr_ + lo * DH + hi * 8); \
    F1 = *(const short8*)(kr_ + (16 + lo) * DH + hi * 8); }
#define LOADV(KI, F0, F1) { \
    F0 = *(const short8*)(vrow0 + (KI) * 64); \
    F1 = *(const short8*)(vrow1 + (KI) * 64); }

  const f32x4 zero = {};
  f32x4 o0_0 = {}, o1_0 = {}, o0_1 = {}, o1_1 = {};
  float dena0 = 0.f, denb0 = 0.f, dena1 = 0.f, denb1 = 0.f;

  short8 ck0, ck1, cv0, cv1, nk0, nk1, nv0, nv1, vp0, vp1;
  LOADK(0, ck0, ck1);
  LOADV(0, cv0, cv1);
  nk0 = ck0; nk1 = ck1; nv0 = cv0; nv1 = cv1;
  vp0 = cv0; vp1 = cv1;

  int tend = KS + d;
  for (int t = 0; t <= tend; ++t) {
    if (t + 1 < tend) { LOADK(t + 1, nk0, nk1); LOADV(t + 1, nv0, nv1); }
    int slot = (t & 1) * 320, slotp = ((t - 1) & 1) * 320;
    int tb = t * BW * 4;
    // ---- row0 QK(t) ----
    if (t < KS) {
      f32x4 s0 = __builtin_amdgcn_mfma_f32_16x16x32_bf16(ck0, aq0, zero, 0, 0, 0);
      f32x4 s1 = __builtin_amdgcn_mfma_f32_16x16x32_bf16(ck1, aq0, zero, 0, 0, 0);
      float p[8];
#pragma unroll
      for (int e = 0; e < 8; ++e) {
        float bv = *(const float*)(sb + (aoff[e] + tb));
        float sv = (e < 4) ? s0[e & 3] : s1[e & 3];
        float ex;
        asm("v_exp_f32 %0, %1" : "=v"(ex) : "v"(sv + bv));
        p[e] = ex;
        if (e & 1) denb0 += ex; else dena0 += ex;
      }
      *(uint2*)(base0 + slot + pwo1) = make_uint2(cvtpk(p[0], p[1]), cvtpk(p[2], p[3]));
      *(uint2*)(base0 + slot + pwo2) = make_uint2(cvtpk(p[4], p[5]), cvtpk(p[6], p[7]));
    }
    // ---- row1 QK(t-d) ----
    if (t >= d && t < KS + d) {
      f32x4 s0 = __builtin_amdgcn_mfma_f32_16x16x32_bf16(ck0, aq1, zero, 0, 0, 0);
      f32x4 s1 = __builtin_amdgcn_mfma_f32_16x16x32_bf16(ck1, aq1, zero, 0, 0, 0);
      float p[8];
#pragma unroll
      for (int e = 0; e < 8; ++e) {
        float bv = *(const float*)(sb + (aoff[e] + rbase1 + tb));
        float sv = (e < 4) ? s0[e & 3] : s1[e & 3];
        float ex;
        asm("v_exp_f32 %0, %1" : "=v"(ex) : "v"(sv + bv));
        p[e] = ex;
        if (e & 1) denb1 += ex; else dena1 += ex;
      }
      *(uint2*)(base1 + slot + pwo1) = make_uint2(cvtpk(p[0], p[1]), cvtpk(p[2], p[3]));
      *(uint2*)(base1 + slot + pwo2) = make_uint2(cvtpk(p[4], p[5]), cvtpk(p[6], p[7]));
    }
    // ---- PV(t-1) for both rows (shares vp) ----
    if (t >= 1 && t <= KS) {
      short8 pa = *(const short8*)(base0 + slotp + pro);
      o0_0 = __builtin_amdgcn_mfma_f32_16x16x32_bf16(pa, vp0, o0_0, 0, 0, 0);
      o1_0 = __builtin_amdgcn_mfma_f32_16x16x32_bf16(pa, vp1, o1_0, 0, 0, 0);
    }
    if (t >= d + 1) {
      short8 pa = *(const short8*)(base1 + slotp + pro);
      o0_1 = __builtin_amdgcn_mfma_f32_16x16x32_bf16(pa, vp0, o0_1, 0, 0, 0);
      o1_1 = __builtin_amdgcn_mfma_f32_16x16x32_bf16(pa, vp1, o1_1, 0, 0, 0);
    }
    vp0 = cv0; vp1 = cv1;
    cv0 = nv0; cv1 = nv1;
    ck0 = nk0; ck1 = nk1;
  }
#undef LOADK
#undef LOADV

#pragma unroll
  for (int r = 0; r < 2; ++r) {
    float den = (r == 0) ? (dena0 + denb0) : (dena1 + denb1);
    den += __shfl_xor(den, 16);
    den += __shfl_xor(den, 32);
    float inv = 1.f / den;
    float dinv[4];
#pragma unroll
    for (int q = 0; q < 4; ++q) dinv[q] = __shfl(inv, hi * 4 + q);
    f32x4 oa = (r == 0) ? o0_0 : o0_1;
    f32x4 ob = (r == 0) ? o1_0 : o1_1;
    size_t ybase = ((size_t)b * 4096 + (size_t)(i0 + r) * 64 + jbase) * 256 + h * DH;
#pragma unroll
    for (int q = 0; q < 4; ++q) {
      int jr = hi * 4 + q;
      y[ybase + (size_t)jr * 256 + lo]      = f2bf(oa[q] * dinv[q]);
      y[ybase + (size_t)jr * 256 + 16 + lo] = f2bf(ob[q] * dinv[q]);
    }
  }
}

__global__ __launch_bounds__(256) void natt_mfma(const ushort* __restrict__ qkvb,
    const ushort* __restrict__ vt, const float* __restrict__ rpb0,
    const float* __restrict__ rpb1, ushort* __restrict__ y) {
  __shared__ float sbias[4 * 13 * 25];         // 5.2 KB (K7 uses a prefix)
  __shared__ unsigned int sP[4 * 4 * 320];     // 20 KB: 4 waves x 2 rows x 2 slots
  // XCD-aware decode: all i-blocks of one (b,h) on one XCD; K13/K7 balanced
  int blk = blockIdx.x;                        // 2048 = 8 xcd * 8 b * 32 ipair
  int xcd = blk & 7, rest = blk >> 3;
  int b = rest >> 5, i0 = (rest & 31) * 2;
  int ho = (xcd - b) & 7;
  if (ho < 4) natt_pair<13>(qkvb, vt, rpb1, y, sbias, sP, b, ho, ho + 4, i0);
  else        natt_pair<7> (qkvb, vt, rpb0, y, sbias, sP, b, ho - 4, ho - 4, i0);
}

extern "C" void kernel_launch(void* const* d_in, const int* in_sizes, int n_in,
                              void* d_out, int out_size, void* d_ws, size_t ws_size,
                              hipStream_t stream) {
  const float* x      = (const float*)d_in[0];
  const float* w_qkv  = (const float*)d_in[1];
  const float* b_qkv  = (const float*)d_in[2];
  const float* rpb0   = (const float*)d_in[3];
  const float* rpb1   = (const float*)d_in[4];
  const float* w_proj = (const float*)d_in[5];
  const float* b_proj = (const float*)d_in[6];
  float* out = (float*)d_out;

  char* ws = (char*)d_ws;
  ushort* qkvb = (ushort*)(ws);                    // 32 MB: [16][GM][32] bf16 (q,k)
  ushort* vt   = (ushort*)(ws + (32u << 20));      // 16 MB: [8*32][GM] bf16 (V^T)
  ushort* yb   = (ushort*)(ws + (48u << 20));      // 16 MB: [GM][256] bf16

  gemm_bt<0><<<1536, 256, 0, stream>>>(x, nullptr, w_qkv, qkvb, vt, nullptr, b_qkv,
                                       0.17677669529663687f * LOG2E);
  natt_mfma<<<2048, 256, 0, stream>>>(qkvb, vt, rpb0, rpb1, yb);
  gemm_bt<1><<<512, 256, 0, stream>>>(nullptr, yb, w_proj, nullptr, nullptr, out,
                                      b_proj, 1.0f);
}

// Round 8
// 192.215 us; speedup vs baseline: 11.0715x; 1.0321x over previous
//
#include <hip/hip_runtime.h>
#include <hip/hip_bf16.h>

typedef __attribute__((ext_vector_type(8))) short short8;
typedef __attribute__((ext_vector_type(4))) float f32x4;

#define GM 32768   // B*H*W
#define DH 32      // head dim
#define LOG2E 1.4426950408889634f

__device__ __forceinline__ ushort f2bf(float f) {
  unsigned int u = __float_as_uint(f);
  u += 0x7FFFu + ((u >> 16) & 1u);   // round-to-nearest-even
  return (ushort)(u >> 16);
}
__device__ __forceinline__ unsigned int cvtpk(float a, float b) {
  unsigned int r;
  asm("v_cvt_pk_bf16_f32 %0, %1, %2" : "=v"(r) : "v"(a), "v"(b));
  return r;
}

// ---- one-time weight cast fp32 -> bf16 (w_qkv 196608 + w_proj 65536) ----
__global__ __launch_bounds__(256) void cast_w(const float* __restrict__ wq,
                                              const float* __restrict__ wp,
                                              ushort* __restrict__ wqb,
                                              ushort* __restrict__ wpb) {
  int idx = (blockIdx.x * 256 + threadIdx.x) * 4;
  const float* src; ushort* dst; int k;
  if (idx < 196608) { src = wq; dst = wqb; k = idx; }
  else              { src = wp; dst = wpb; k = idx - 196608; }
  float4 t = *(const float4*)(src + k);
  ushort4 o;
  o.x = f2bf(t.x); o.y = f2bf(t.y); o.z = f2bf(t.z); o.w = f2bf(t.w);
  *(ushort4*)(dst + k) = o;
}

// ---- bf16 MFMA GEMM, software-pipelined K-loop (prefetch kt+1 over MFMA kt) ----
// MODE 0: A=x fp32 (fused cast), B=wqb bf16; epilogue: q/k -> [sel*8+h][pos][32],
//         V -> transposed vt[h*32+d][pos] via XOR-swizzled [col][row] staging.
// MODE 1: A=yb bf16, B=wpb bf16; epilogue -> fp32 row-major + bias.
template<int MODE>
__global__ __launch_bounds__(256) void gemm_bt(
    const float* __restrict__ Af, const ushort* __restrict__ Ab,
    const ushort* __restrict__ Btb,
    ushort* __restrict__ Cb, ushort* __restrict__ Vt,
    float* __restrict__ Cf, const float* __restrict__ bias, float scale) {
  const int BM = 128, BN = 128, BK = 64, K = 256;
  __shared__ int4 sAB[2048];               // 32 KB: A+B tiles / C staging
  int4* sA4 = sAB;
  int4* sB4 = sAB + 1024;

  int id = blockIdx.x, xcd = id & 7, rest = id >> 3;
  int bm, bn;
  if (MODE == 0) { bm = xcd * 32 + rest / 6;    bn = rest % 6; }
  else           { bm = xcd * 32 + (rest >> 1); bn = rest & 1; }

  int tid = threadIdx.x, lane = tid & 63, wid = tid >> 6;
  int wm = (wid >> 1) * 64, wn = (wid & 1) * 64;
  int lo = lane & 15, hi = lane >> 4;

  f32x4 acc[4][4] = {};
  float4 raf[8], raf2[8];
  int4 rai[4], rai2[4], rbi[4], rbi2[4];

#define GLOADA(KT, RAF, RAI) { _Pragma("unroll") \
  for (int ii = 0; ii < 4; ++ii) { int cid = tid + ii * 256, rr = cid >> 3, cc = cid & 7; \
    if (MODE == 0) { const float* p = Af + (size_t)(bm * BM + rr) * K + (KT) * BK + cc * 8; \
      RAF[2*ii] = *(const float4*)p; RAF[2*ii+1] = *(const float4*)(p + 4); } \
    else RAI[ii] = *(const int4*)(Ab + (size_t)(bm * BM + rr) * K + (KT) * BK + cc * 8); } }
#define GLOADB(KT, RBI) { _Pragma("unroll") \
  for (int ii = 0; ii < 4; ++ii) { int cid = tid + ii * 256, rr = cid >> 3, cc = cid & 7; \
    RBI[ii] = *(const int4*)(Btb + (size_t)(bn * BN + rr) * K + (KT) * BK + cc * 8); } }

  GLOADA(0, raf, rai);
  GLOADB(0, rbi);

#pragma unroll
  for (int kt = 0; kt < 4; ++kt) {
#pragma unroll
    for (int ii = 0; ii < 4; ++ii) {
      int cid = tid + ii * 256, rr = cid >> 3, cc = cid & 7;
      int4 av;
      if (MODE == 0)
        av = make_int4(cvtpk(raf[2*ii].x, raf[2*ii].y), cvtpk(raf[2*ii].z, raf[2*ii].w),
                       cvtpk(raf[2*ii+1].x, raf[2*ii+1].y), cvtpk(raf[2*ii+1].z, raf[2*ii+1].w));
      else av = rai[ii];
      sA4[rr * 8 + (cc ^ (rr & 7))] = av;
      sB4[rr * 8 + (cc ^ (rr & 7))] = rbi[ii];
    }
    __syncthreads();
    if (kt < 3) { GLOADA(kt + 1, raf2, rai2); GLOADB(kt + 1, rbi2); }
#pragma unroll
    for (int ks = 0; ks < 2; ++ks) {
      short8 af[4], bfr[4];
#pragma unroll
      for (int mi = 0; mi < 4; ++mi) {
        int r = wm + mi * 16 + lo, c = ks * 4 + hi;
        af[mi] = ((const short8*)sA4)[r * 8 + (c ^ (r & 7))];
      }
#pragma unroll
      for (int nj = 0; nj < 4; ++nj) {
        int r = wn + nj * 16 + lo, c = ks * 4 + hi;
        bfr[nj] = ((const short8*)sB4)[r * 8 + (c ^ (r & 7))];
      }
#pragma unroll
      for (int mi = 0; mi < 4; ++mi)
#pragma unroll
        for (int nj = 0; nj < 4; ++nj)
          acc[mi][nj] = __builtin_amdgcn_mfma_f32_16x16x32_bf16(
              af[mi], bfr[nj], acc[mi][nj], 0, 0, 0);
    }
    __syncthreads();
    if (kt < 3) {
#pragma unroll
      for (int ii = 0; ii < 4; ++ii) {
        rai[ii] = rai2[ii]; rbi[ii] = rbi2[ii];
        raf[2*ii] = raf2[2*ii]; raf[2*ii+1] = raf2[2*ii+1];
      }
    }
  }
#undef GLOADA
#undef GLOADB

  if (MODE == 0) {
    float sc = (bn < 2) ? scale : 1.0f;
    ushort* sC = (ushort*)sAB;
    if (bn < 4) {
      // q/k: row-major staging [row][col XOR-chunked] -> coalesced 16B stores
#pragma unroll
      for (int mi = 0; mi < 4; ++mi)
#pragma unroll
        for (int nj = 0; nj < 4; ++nj)
#pragma unroll
          for (int r = 0; r < 4; ++r) {
            int row = wm + mi * 16 + hi * 4 + r;
            int col = wn + nj * 16 + lo;
            float v = (acc[mi][nj][r] + bias[bn * BN + col]) * sc;
            sC[row * 128 + (((col >> 3) ^ (row & 15)) << 3) + (col & 7)] = f2bf(v);
          }
      __syncthreads();
      int sel = bn >> 1;
      size_t base0 = ((size_t)(sel * 8 + (bn & 1) * 4) * GM + (size_t)bm * BM) * DH;
#pragma unroll
      for (int p8 = 0; p8 < 8; ++p8) {
        int o = p8 * 256 + tid;
        int hh = o >> 9, row = (o >> 2) & 127, q = o & 3;
        int4 val = *(const int4*)(sC + row * 128 + (((hh * 4 + q) ^ (row & 15)) << 3));
        *(int4*)(Cb + base0 + (size_t)hh * GM * DH + row * DH + q * 8) = val;
      }
    } else {
      // V: TRANSPOSED staging [col][row XOR-chunked] -> coalesced b128 reads+stores
#pragma unroll
      for (int mi = 0; mi < 4; ++mi)
#pragma unroll
        for (int nj = 0; nj < 4; ++nj)
#pragma unroll
          for (int r = 0; r < 4; ++r) {
            int row = wm + mi * 16 + hi * 4 + r;
            int col = wn + nj * 16 + lo;
            float v = acc[mi][nj][r] + bias[bn * BN + col];
            sC[col * 128 + (((row >> 3) ^ (col & 15)) << 3) + (row & 7)] = f2bf(v);
          }
      __syncthreads();
      int hb32 = (bn - 4) * 128;
#pragma unroll
      for (int p8 = 0; p8 < 8; ++p8) {
        int chunk = tid & 15, colg = p8 * 16 + (tid >> 4);
        int4 val = *(const int4*)(sC + colg * 128 + ((chunk ^ (colg & 15)) << 3));
        *(int4*)(Vt + (size_t)(hb32 + colg) * GM + (size_t)bm * BM + chunk * 8) = val;
      }
    }
  } else {
#pragma unroll
    for (int mi = 0; mi < 4; ++mi)
#pragma unroll
      for (int nj = 0; nj < 4; ++nj)
#pragma unroll
        for (int r = 0; r < 4; ++r) {
          int row = bm * BM + wm + mi * 16 + hi * 4 + r;
          int col = bn * BN + wn + nj * 16 + lo;
          Cf[(size_t)row * 256 + col] = acc[mi][nj][r] + bias[col];
        }
  }
}

// ---- MFMA neighborhood attention v6: one wave = FOUR adjacent i-rows ----
// Rows i0..i0+3 share all K/V loads (shift d_r in {0..3}); four independent
// QK->exp->PV chains; per-row skewed PV(t-1) through double-buffered LDS P.
template<int KS>
__device__ __forceinline__ void natt_quad(const ushort* __restrict__ qkvb,
                                          const ushort* __restrict__ vt,
                                          const float* __restrict__ rpb,
                                          ushort* __restrict__ y,
                                          float* sbias, unsigned int* sP,
                                          int b, int hl, int h, int i0) {
  const int NHF = KS / 2, BW = 2 * KS - 1, LK = 64 - KS, TS = KS * BW;
  int tid = threadIdx.x;
  int lane = tid & 63, w = tid >> 6, lo = lane & 15, hi = lane >> 4;

  int wi_[4], d_[4], rb_[4];
#pragma unroll
  for (int r = 0; r < 4; ++r) {
    int i = i0 + r;
    int wi = i - NHF; wi = wi < 0 ? 0 : (wi > LK ? LK : wi);
    wi_[r] = wi;
  }
  int wi0 = wi_[0];
#pragma unroll
  for (int r = 0; r < 4; ++r) {
    d_[r] = wi_[r] - wi0;
    rb_[r] = (r * TS - d_[r] * BW) * 4;
  }
  int d3 = d_[3];

  // stage 4 Toeplitz bias tables (x log2e) + sentinel region (-1e30 -> exp2=0)
  for (int t = tid; t < 8 * TS + 2 * BW; t += 256) {
    float v = -1e30f;
    if (t < 4 * TS) {
      int r = t / TS, tt = t - r * TS;
      int ki = tt / BW, cb = tt - ki * BW;
      int i = i0 + r;
      int pi = NHF + ((i < NHF) ? (NHF - i) : 0) + ((i >= 64 - NHF) ? (63 - NHF - i) : 0);
      v = rpb[((size_t)hl * BW + pi + ki) * BW + cb] * LOG2E;
    }
    sbias[t] = v;
  }
  __syncthreads();

  const ushort* qb = qkvb;
  const ushort* kb = qkvb + (size_t)8 * GM * DH;

  int jbase = 16 * w;
  int j = jbase + lo;
  size_t posQ = (size_t)h * GM + b * 4096 + i0 * 64 + j;
  short8 aq0 = *(const short8*)(qb + posQ * DH + hi * 8);
  short8 aq1 = *(const short8*)(qb + (posQ + 64) * DH + hi * 8);
  short8 aq2 = *(const short8*)(qb + (posQ + 128) * DH + hi * 8);
  short8 aq3 = *(const short8*)(qb + (posQ + 192) * DH + hi * 8);

  int wj16 = jbase - NHF; wj16 = wj16 < 0 ? 0 : (wj16 > LK ? LK : wj16);
  int cbase = wj16 < 32 ? wj16 : 32;
  int wj = j - NHF; wj = wj < 0 ? 0 : (wj > LK ? LK : wj);

  int aoff[8];
#pragma unroll
  for (int t = 0; t < 8; ++t) {
    int c = cbase + (t >> 2) * 16 + hi * 4 + (t & 3);
    int idx = c - j + (KS - 1);
    bool valid = (c >= wj) && (c < wj + KS);
    aoff[t] = valid ? idx * 4 : 4 * TS * 4;
  }

  int pwo1 = lo * 20 + 2 * hi, pwo2 = lo * 20 + 8 + 2 * hi, pro = lo * 20 + 4 * hi;
  const char* sb = (const char*)sbias;
  const ushort* kband = kb + ((size_t)h * GM + b * 4096 + (size_t)wi0 * 64 + cbase) * DH;
  const ushort* vrow0 = vt + ((size_t)h * DH + lo) * GM
                        + ((size_t)b * 4096 + (size_t)wi0 * 64 + cbase + hi * 8);
  const ushort* vrow1 = vrow0 + (size_t)16 * GM;

#define LOADK(KI, F0, F1) { const ushort* kr_ = kband + (KI) * 64 * DH; \
    F0 = *(const short8*)(kr_ + lo * DH + hi * 8); \
    F1 = *(const short8*)(kr_ + (16 + lo) * DH + hi * 8); }
#define LOADV(KI, F0, F1) { \
    F0 = *(const short8*)(vrow0 + (KI) * 64); \
    F1 = *(const short8*)(vrow1 + (KI) * 64); }

  const f32x4 zero = {};
  f32x4 o0_0 = {}, o1_0 = {}, o0_1 = {}, o1_1 = {};
  f32x4 o0_2 = {}, o1_2 = {}, o0_3 = {}, o1_3 = {};
  float dena0 = 0.f, denb0 = 0.f, dena1 = 0.f, denb1 = 0.f;
  float dena2 = 0.f, denb2 = 0.f, dena3 = 0.f, denb3 = 0.f;

  short8 ck0, ck1, cv0, cv1, nk0, nk1, nv0, nv1, vp0, vp1;
  LOADK(0, ck0, ck1);
  LOADV(0, cv0, cv1);
  nk0 = ck0; nk1 = ck1; nv0 = cv0; nv1 = cv1;
  vp0 = cv0; vp1 = cv1;

#define ROWQK(R, AQ, DENA, DENB) \
  if (t >= d_[R] && t < KS + d_[R]) { \
    f32x4 s0 = __builtin_amdgcn_mfma_f32_16x16x32_bf16(ck0, AQ, zero, 0, 0, 0); \
    f32x4 s1 = __builtin_amdgcn_mfma_f32_16x16x32_bf16(ck1, AQ, zero, 0, 0, 0); \
    float p[8]; \
    _Pragma("unroll") \
    for (int e = 0; e < 8; ++e) { \
      float bv = *(const float*)(sb + (aoff[e] + rb_[R] + tb)); \
      float sv = (e < 4) ? s0[e & 3] : s1[e & 3]; \
      float ex; asm("v_exp_f32 %0, %1" : "=v"(ex) : "v"(sv + bv)); \
      p[e] = ex; if (e & 1) DENB += ex; else DENA += ex; \
    } \
    unsigned int* bp = sP + (w * 8 + R * 2) * 320 + slot; \
    *(uint2*)(bp + pwo1) = make_uint2(cvtpk(p[0], p[1]), cvtpk(p[2], p[3])); \
    *(uint2*)(bp + pwo2) = make_uint2(cvtpk(p[4], p[5]), cvtpk(p[6], p[7])); \
  }
#define ROWPV(R, O0, O1) \
  if (t > d_[R] && t <= KS + d_[R]) { \
    const unsigned int* bp = sP + (w * 8 + R * 2) * 320 + slotp; \
    short8 pa = *(const short8*)(bp + pro); \
    O0 = __builtin_amdgcn_mfma_f32_16x16x32_bf16(pa, vp0, O0, 0, 0, 0); \
    O1 = __builtin_amdgcn_mfma_f32_16x16x32_bf16(pa, vp1, O1, 0, 0, 0); \
  }

  int tend = KS + d3;
  for (int t = 0; t <= tend; ++t) {
    if (t + 1 < tend) { LOADK(t + 1, nk0, nk1); LOADV(t + 1, nv0, nv1); }
    int slot = (t & 1) * 320, slotp = ((t - 1) & 1) * 320;
    int tb = t * BW * 4;
    ROWQK(0, aq0, dena0, denb0)
    ROWQK(1, aq1, dena1, denb1)
    ROWQK(2, aq2, dena2, denb2)
    ROWQK(3, aq3, dena3, denb3)
    ROWPV(0, o0_0, o1_0)
    ROWPV(1, o0_1, o1_1)
    ROWPV(2, o0_2, o1_2)
    ROWPV(3, o0_3, o1_3)
    vp0 = cv0; vp1 = cv1;
    cv0 = nv0; cv1 = nv1;
    ck0 = nk0; ck1 = nk1;
  }
#undef LOADK
#undef LOADV
#undef ROWQK
#undef ROWPV

#define ROWOUT(R, DENA, DENB, O0, O1) { \
  float den = DENA + DENB; \
  den += __shfl_xor(den, 16); den += __shfl_xor(den, 32); \
  float inv = 1.f / den; \
  size_t ybase = ((size_t)b * 4096 + (size_t)(i0 + R) * 64 + jbase) * 256 + h * DH; \
  _Pragma("unroll") \
  for (int q2 = 0; q2 < 4; ++q2) { \
    float dv = __shfl(inv, hi * 4 + q2); \
    y[ybase + (size_t)(hi * 4 + q2) * 256 + lo]      = f2bf(O0[q2] * dv); \
    y[ybase + (size_t)(hi * 4 + q2) * 256 + 16 + lo] = f2bf(O1[q2] * dv); \
  } }

  ROWOUT(0, dena0, denb0, o0_0, o1_0)
  ROWOUT(1, dena1, denb1, o0_1, o1_1)
  ROWOUT(2, dena2, denb2, o0_2, o1_2)
  ROWOUT(3, dena3, denb3, o0_3, o1_3)
#undef ROWOUT
}

__global__ __launch_bounds__(256) void natt_mfma(const ushort* __restrict__ qkvb,
    const ushort* __restrict__ vt, const float* __restrict__ rpb0,
    const float* __restrict__ rpb1, ushort* __restrict__ y) {
  __shared__ float sbias[2656];            // 8*TS+2*BW for K13 = 2650
  __shared__ unsigned int sP[10240];       // 4 waves x 4 rows x 2 slots x 320
  int blk = blockIdx.x;                    // 1024 = 8 xcd * 8 b * 16 quad
  int xcd = blk & 7, rest = blk >> 3;
  int b = rest >> 4, i0 = (rest & 15) * 4;
  int ho = (xcd - b) & 7;
  if (ho < 4) natt_quad<13>(qkvb, vt, rpb1, y, sbias, sP, b, ho, ho + 4, i0);
  else        natt_quad<7> (qkvb, vt, rpb0, y, sbias, sP, b, ho - 4, ho - 4, i0);
}

extern "C" void kernel_launch(void* const* d_in, const int* in_sizes, int n_in,
                              void* d_out, int out_size, void* d_ws, size_t ws_size,
                              hipStream_t stream) {
  const float* x      = (const float*)d_in[0];
  const float* w_qkv  = (const float*)d_in[1];
  const float* b_qkv  = (const float*)d_in[2];
  const float* rpb0   = (const float*)d_in[3];
  const float* rpb1   = (const float*)d_in[4];
  const float* w_proj = (const float*)d_in[5];
  const float* b_proj = (const float*)d_in[6];
  float* out = (float*)d_out;

  char* ws = (char*)d_ws;
  ushort* qkvb = (ushort*)(ws);                         // 32 MB: [16][GM][32] (q,k)
  ushort* vt   = (ushort*)(ws + (32u << 20));           // 16 MB: [8*32][GM] (V^T)
  ushort* yb   = (ushort*)(ws + (48u << 20));           // 16 MB: [GM][256]
  ushort* wqb  = (ushort*)(ws + (64u << 20));           // 384 KB
  ushort* wpb  = (ushort*)(ws + (64u << 20) + 393216);  // 128 KB

  cast_w<<<256, 256, 0, stream>>>(w_qkv, w_proj, wqb, wpb);
  gemm_bt<0><<<1536, 256, 0, stream>>>(x, nullptr, wqb, qkvb, vt, nullptr, b_qkv,
                                       0.17677669529663687f * LOG2E);
  natt_mfma<<<1024, 256, 0, stream>>>(qkvb, vt, rpb0, rpb1, yb);
  gemm_bt<1><<<512, 256, 0, stream>>>(nullptr, yb, wpb, nullptr, nullptr, out,
                                      b_proj, 1.0f);
}